// Round 5
// baseline (953.404 us; speedup 1.0000x reference)
//
#include <hip/hip_runtime.h>
#include <hip/hip_bf16.h>
#include <cstdint>
#include <cstddef>

// Cross_attention_dl: B=4, S=2048, D1=512, D2=1024. ALL I/O f32.
// Split-precision (bf16 hi/lo plane) MFMA pipeline; operands pre-split in
// global. Round 13: gemm_split K-loop restructured like round-11's scores
// kernel -- all 16 ds_read_b128 issued up front in wait-group order
// (af 8, bg-lo 4, bg-hi 4), MFMA half (c=0,1) runs under compiler-counted
// lgkm waits while the bg tail drains, then lgkm0+barrier+prefetch, MFMA
// half (c=2,3) covers the gld16 issue. Round-12 counters: stage-2 QK proj
// 133us @ 775 TF (MfmaUtil 34%) and stage-1 PV ~105us @ 490 TF (MfmaUtil
// 18%, 1 block/CU) -- both serialized LDS-read -> MFMA per iteration.
// Accumulation order per output element unchanged (absmax identical).

typedef __bf16 bf16;
typedef __attribute__((ext_vector_type(8))) __bf16 bf16x8;
typedef __attribute__((ext_vector_type(4))) __bf16 bf16x4;
typedef __attribute__((ext_vector_type(4))) float f32x4;

__device__ __forceinline__ void gld16(const bf16* g, bf16* s) {
    __builtin_amdgcn_global_load_lds(
        (const __attribute__((address_space(1))) void*)g,
        (__attribute__((address_space(3))) void*)s, 16, 0, 0);
}

// gfx9 waitcnt imm: vmcnt[3:0]+[15:14], expcnt[6:4], lgkmcnt[11:8]
#define WAIT_VM8   __builtin_amdgcn_s_waitcnt(8 | (7 << 4) | (0xF << 8))
#define WAIT_VM0   __builtin_amdgcn_s_waitcnt(0 | (7 << 4) | (0xF << 8))
#define WAIT_LGKM0 __builtin_amdgcn_s_waitcnt(0xF | (7 << 4) | (0 << 8) | (3 << 14))

// element offset of logical (row, col-group g) in a swizzled [rows][64] tile
__device__ __forceinline__ int swz(int row, int g) {
    return row * 64 + ((g ^ (row & 7)) << 3);
}

// ---------------------------------------------------------------------------
// 128^2-tile kernel: projections / PV / cfg==0 paths.
// C = A @ B^T over bf16 planes. All strides in ELEMENTS. Flat 1-D grid with
// XCD supertile decode. Requires grid % 128 == 0.
// split=3: phases (A0,B0),(A1,B0),(A0,B1); split=1: (A0,B0) only.
// bias: col gcol < nsplit -> bias[gcol], else bias2[gcol-nsplit].
// mode 0: f32 C[z][m][n] = acc (+resid*scale)
// mode 1: bf16 plane-pair row-major: C[p][z*M+m][n] = acc + bias (+resid*scale)
// mode 2: bf16 plane-pair transposed: C[b][p][n][s] (b=grow>>11, s=grow&2047)
__global__ __launch_bounds__(256) void gemm_split(
    const bf16* __restrict__ A, long lda, long psA, long bsA,
    const bf16* __restrict__ B, long ldb, long psB, long bsB,
    void* __restrict__ C, long ldc, long psC, long bsC, int mode,
    const float* __restrict__ bias, const float* __restrict__ bias2, int nsplit,
    const float* __restrict__ resid, long ldr, long bsR,
    const float* __restrict__ scale,
    int K, int split, int nx, int ny)
{
    __shared__ __align__(16) bf16 As[2][128 * 64];
    __shared__ __align__(16) bf16 Bs[2][128 * 64];

    const int t    = threadIdx.x;
    const int wave = t >> 6;
    const int lane = t & 63;
    const int wr   = wave >> 1;
    const int wc   = wave & 1;
    const int r16  = lane & 15;
    const int quad = lane >> 4;

    const int g    = blockIdx.x;
    const int xcd  = g & 7;
    const int tk   = g >> 3;
    const int nst8 = gridDim.x >> 7;              // supertiles per XCD
    const int st   = xcd * nst8 + (tk >> 4);      // global supertile id
    const int p    = tk & 15;                     // position in 4x4 supertile
    const int snx  = nx >> 2, sny = ny >> 2;
    const int spz  = snx * sny;
    const int zz   = st / spz;
    const int rS   = st - zz * spz;
    const int sy   = rS / snx;
    const int sx   = rS - sy * snx;
    const int yb   = sy * 4 + (p >> 2);
    const int xb   = sx * 4 + (p & 3);
    const long z   = zz;

    const long row0 = (long)yb * 128;
    const long col0 = (long)xb * 128;

    const int srow = (lane >> 3);                  // 0..7 within an 8-row chunk
    const int scol = ((lane & 7) ^ srow) * 8;      // swizzled col group this lane fetches

    const int ktiles = K >> 6;
    const int T = split * ktiles;

    const bf16* Az = A + z * bsA;
    const bf16* Bz = B + z * bsB;

    auto prefetch = [&](int ti, int buf) {
        const int ph = ti / ktiles;
        const int kt = (ti - ph * ktiles) << 6;
        const bf16* Ab = Az + (ph == 1 ? psA : 0);
        const bf16* Bb = Bz + (ph == 2 ? psB : 0);
#pragma unroll
        for (int p2 = 0; p2 < 4; ++p2) {
            const int chunk = wave * 32 + p2 * 8;   // 8 rows per 1KB wave store
            gld16(Ab + (row0 + chunk + srow) * lda + kt + scol, &As[buf][chunk * 64]);
            gld16(Bb + (col0 + chunk + srow) * ldb + kt + scol, &Bs[buf][chunk * 64]);
        }
    };

    f32x4 acc[4][4];
#pragma unroll
    for (int r = 0; r < 4; ++r)
#pragma unroll
        for (int c = 0; c < 4; ++c)
            acc[r][c] = (f32x4){0.f, 0.f, 0.f, 0.f};

    prefetch(0, 0);
    prefetch(1, 1);
    for (int ti = 0; ti < T; ++ti) {
        const int cur = ti & 1;
        if (ti + 1 < T) WAIT_VM8; else WAIT_VM0;   // oldest 8 (cur tile) landed
        __builtin_amdgcn_s_barrier();

        // Issue ALL fragment reads in wait-group order: af (8), bg cols 0-1
        // (4), bg cols 2-3 (4). Half-A MFMAs run under counted lgkm waits
        // while the bg tail drains.
        bf16x8 af[2][4], bg[2][4];
#pragma unroll
        for (int kk = 0; kk < 2; ++kk) {            // group 1: af (8 reads)
            const int g0 = (kk << 2) + quad;
#pragma unroll
            for (int r = 0; r < 4; ++r)
                af[kk][r] = *reinterpret_cast<const bf16x8*>(&As[cur][swz(wr * 64 + r * 16 + r16, g0)]);
        }
#pragma unroll
        for (int kk = 0; kk < 2; ++kk) {            // group 2: bg c=0,1 (4 reads)
            const int g0 = (kk << 2) + quad;
#pragma unroll
            for (int c = 0; c < 2; ++c)
                bg[kk][c] = *reinterpret_cast<const bf16x8*>(&Bs[cur][swz(wc * 64 + c * 16 + r16, g0)]);
        }
#pragma unroll
        for (int kk = 0; kk < 2; ++kk) {            // group 3: bg c=2,3 (4 reads)
            const int g0 = (kk << 2) + quad;
#pragma unroll
            for (int c = 2; c < 4; ++c)
                bg[kk][c] = *reinterpret_cast<const bf16x8*>(&Bs[cur][swz(wc * 64 + c * 16 + r16, g0)]);
        }

        // Half A: needs af + bg[.][0,1] (oldest 12) -- counted lgkm wait.
        __builtin_amdgcn_s_setprio(1);
#pragma unroll
        for (int kk = 0; kk < 2; ++kk)
#pragma unroll
            for (int r = 0; r < 4; ++r)
#pragma unroll
                for (int c = 0; c < 2; ++c)
                    acc[r][c] = __builtin_amdgcn_mfma_f32_16x16x32_bf16(af[kk][r], bg[kk][c], acc[r][c], 0, 0, 0);
        __builtin_amdgcn_s_setprio(0);

        __builtin_amdgcn_sched_barrier(0);          // pin all read issues above
        WAIT_LGKM0;                                 // all 16 reads complete
        __builtin_amdgcn_s_barrier();               // LDS WAR fence: buf[cur] free
        if (ti + 2 < T) prefetch(ti + 2, cur);      // 8 gld16, covered by half B

        // Half B: frags resident.
        __builtin_amdgcn_s_setprio(1);
#pragma unroll
        for (int kk = 0; kk < 2; ++kk)
#pragma unroll
            for (int r = 0; r < 4; ++r)
#pragma unroll
                for (int c = 2; c < 4; ++c)
                    acc[r][c] = __builtin_amdgcn_mfma_f32_16x16x32_bf16(af[kk][r], bg[kk][c], acc[r][c], 0, 0, 0);
        __builtin_amdgcn_s_setprio(0);
    }

    const float scv = resid ? *scale : 0.f;

#pragma unroll
    for (int r = 0; r < 4; ++r) {
#pragma unroll
        for (int c = 0; c < 4; ++c) {
            long gcol = col0 + wc * 64 + c * 16 + r16;
            float bv = 0.f;
            if (bias) bv = (gcol < nsplit) ? bias[gcol] : bias2[gcol - nsplit];
#pragma unroll
            for (int i = 0; i < 4; ++i) {
                long grow = row0 + wr * 64 + r * 16 + quad * 4 + i;
                float val = acc[r][c][i] + bv;
                if (mode == 0) {
                    if (resid) val += resid[z * bsR + grow * ldr + gcol] * scv;
                    ((float*)C)[z * bsC + grow * ldc + gcol] = val;
                } else if (mode == 1) {
                    if (resid) val += resid[z * bsR + grow * ldr + gcol] * scv;
                    bf16* Cb = (bf16*)C + z * bsC;
                    bf16 h = (bf16)val;
                    Cb[grow * ldc + gcol] = h;
                    Cb[psC + grow * ldc + gcol] = (bf16)(val - (float)h);
                } else {
                    long b = grow >> 11, s = grow & 2047;
                    bf16* Cb = (bf16*)C + b * bsC;
                    bf16 h = (bf16)val;
                    Cb[gcol * ldc + s] = h;
                    Cb[psC + gcol * ldc + s] = (bf16)(val - (float)h);
                }
            }
        }
    }
}

// ---------------------------------------------------------------------------
// 256^2-tile 8-wave scores kernel: C[z][2048][2048] f32 = A @ B^T, split=3.
// Grid is EXACTLY 256 blocks (8x8 tiles x z=4) = 1 block/CU, 128KiB LDS.
// All 24 ds_read_b128 issued up front in wait-group order; MFMA quadrants
// run under compiler-counted lgkm waits; 2 barriers per K-tile; counted
// vmcnt(8) at top with 2-deep prefetch.
__global__ __launch_bounds__(512) void gemm256_scores(
    const bf16* __restrict__ A, long lda, long psA, long bsA,
    const bf16* __restrict__ B, long ldb, long psB, long bsB,
    float* __restrict__ C, long ldc, long bsC, int K)
{
    __shared__ __align__(16) bf16 As[2][256 * 64];   // 64 KiB
    __shared__ __align__(16) bf16 Bs[2][256 * 64];   // 64 KiB

    const int t    = threadIdx.x;
    const int wave = t >> 6;          // 0..7
    const int lane = t & 63;
    const int wm   = wave >> 2;       // 0..1 -> 128-row half
    const int wn   = wave & 3;        // 0..3 -> 64-col slice
    const int r16  = lane & 15;
    const int quad = lane >> 4;

    // XCD-contiguous decode: 32 consecutive tiles per XCD, row-major within z
    const int g   = blockIdx.x;
    const int idx = (g & 7) * 32 + (g >> 3);
    const int z   = idx >> 6;
    const int t6  = idx & 63;
    const int ty  = t6 >> 3;
    const int tx  = t6 & 7;
    const long row0 = (long)ty * 256;
    const long col0 = (long)tx * 256;

    const int srow = lane >> 3;                    // 0..7 in an 8-row chunk
    const int scol = ((lane & 7) ^ srow) * 8;      // pre-swizzled source group

    const int ktiles = K >> 6;
    const int T = 3 * ktiles;                      // split=3 phases

    const bf16* Az = A + (long)z * bsA;
    const bf16* Bz = B + (long)z * bsB;

    auto prefetch = [&](int ti, int buf) {
        const int ph = ti / ktiles;
        const int kt = (ti - ph * ktiles) << 6;
        const bf16* Ab = Az + (ph == 1 ? psA : 0);
        const bf16* Bb = Bz + (ph == 2 ? psB : 0);
#pragma unroll
        for (int p2 = 0; p2 < 4; ++p2) {           // wave covers 32 rows of A and B
            const int chunk = wave * 32 + p2 * 8;  // 8 rows per 1KiB wave store
            gld16(Ab + (row0 + chunk + srow) * lda + kt + scol, &As[buf][chunk * 64]);
            gld16(Bb + (col0 + chunk + srow) * ldb + kt + scol, &Bs[buf][chunk * 64]);
        }
    };

    f32x4 acc[8][4];
#pragma unroll
    for (int r = 0; r < 8; ++r)
#pragma unroll
        for (int c = 0; c < 4; ++c)
            acc[r][c] = (f32x4){0.f, 0.f, 0.f, 0.f};

    prefetch(0, 0);
    prefetch(1, 1);
    for (int ti = 0; ti < T; ++ti) {
        const int cur = ti & 1;
        if (ti + 1 < T) WAIT_VM8; else WAIT_VM0;    // oldest 8 (tile ti) landed
        __builtin_amdgcn_s_barrier();

        // Issue ALL fragment reads in wait-group order.
        bf16x8 afA[4][2], afB[4][2], bg[2][2][2];
#pragma unroll
        for (int kk = 0; kk < 2; ++kk) {            // group 1: afA (8 reads)
            const int g0 = (kk << 2) + quad;
#pragma unroll
            for (int r = 0; r < 4; ++r)
                afA[r][kk] = *reinterpret_cast<const bf16x8*>(
                    &As[cur][swz(wm * 128 + r * 16 + r16, g0)]);
        }
#pragma unroll
        for (int kk = 0; kk < 2; ++kk) {            // group 2: bg0 (4 reads)
            const int g0 = (kk << 2) + quad;
#pragma unroll
            for (int c = 0; c < 2; ++c)
                bg[0][c][kk] = *reinterpret_cast<const bf16x8*>(
                    &Bs[cur][swz(wn * 64 + c * 16 + r16, g0)]);
        }
#pragma unroll
        for (int kk = 0; kk < 2; ++kk) {            // group 3: bg1 (4 reads)
            const int g0 = (kk << 2) + quad;
#pragma unroll
            for (int c = 0; c < 2; ++c)
                bg[1][c][kk] = *reinterpret_cast<const bf16x8*>(
                    &Bs[cur][swz(wn * 64 + (2 + c) * 16 + r16, g0)]);
        }
#pragma unroll
        for (int kk = 0; kk < 2; ++kk) {            // group 4: afB (8 reads)
            const int g0 = (kk << 2) + quad;
#pragma unroll
            for (int r = 0; r < 4; ++r)
                afB[r][kk] = *reinterpret_cast<const bf16x8*>(
                    &As[cur][swz(wm * 128 + (4 + r) * 16 + r16, g0)]);
        }

        // Q00/Q01 under counted lgkm waits; bg1/afB drain underneath.
        __builtin_amdgcn_s_setprio(1);
#pragma unroll
        for (int kk = 0; kk < 2; ++kk)
#pragma unroll
            for (int r = 0; r < 4; ++r)
#pragma unroll
                for (int c = 0; c < 2; ++c)
                    acc[r][c] = __builtin_amdgcn_mfma_f32_16x16x32_bf16(
                        afA[r][kk], bg[0][c][kk], acc[r][c], 0, 0, 0);
#pragma unroll
        for (int kk = 0; kk < 2; ++kk)
#pragma unroll
            for (int r = 0; r < 4; ++r)
#pragma unroll
                for (int c = 0; c < 2; ++c)
                    acc[r][2 + c] = __builtin_amdgcn_mfma_f32_16x16x32_bf16(
                        afA[r][kk], bg[1][c][kk], acc[r][2 + c], 0, 0, 0);
        __builtin_amdgcn_s_setprio(0);

        __builtin_amdgcn_sched_barrier(0);          // pin all read issues above
        WAIT_LGKM0;                                 // all 24 reads complete
        __builtin_amdgcn_s_barrier();               // LDS WAR fence: buf[cur] free
        if (ti + 2 < T) prefetch(ti + 2, cur);      // 8 gld16, covered by Q10/Q11

        __builtin_amdgcn_s_setprio(1);
#pragma unroll
        for (int kk = 0; kk < 2; ++kk)
#pragma unroll
            for (int r = 0; r < 4; ++r)
#pragma unroll
                for (int c = 0; c < 2; ++c)
                    acc[4 + r][c] = __builtin_amdgcn_mfma_f32_16x16x32_bf16(
                        afB[r][kk], bg[0][c][kk], acc[4 + r][c], 0, 0, 0);
#pragma unroll
        for (int kk = 0; kk < 2; ++kk)
#pragma unroll
            for (int r = 0; r < 4; ++r)
#pragma unroll
                for (int c = 0; c < 2; ++c)
                    acc[4 + r][2 + c] = __builtin_amdgcn_mfma_f32_16x16x32_bf16(
                        afB[r][kk], bg[1][c][kk], acc[4 + r][2 + c], 0, 0, 0);
        __builtin_amdgcn_s_setprio(0);
    }

#pragma unroll
    for (int r = 0; r < 8; ++r) {
#pragma unroll
        for (int c = 0; c < 4; ++c) {
            const long gcol = col0 + wn * 64 + c * 16 + r16;
#pragma unroll
            for (int i = 0; i < 4; ++i) {
                const long grow = row0 + wm * 128 + r * 16 + quad * 4 + i;
                C[(long)z * bsC + grow * ldc + gcol] = acc[r][c][i];
            }
        }
    }
}

// Row softmax over 2048 f32 cols; writes P IN PLACE as bf16 hi plane (cols
// [0,2048) of the row's 4096 bf16 slots) and lo plane (cols [2048,4096)).
__global__ __launch_bounds__(256) void softmax_planes(float* __restrict__ S)
{
    __shared__ float redm[4], reds[4];
    float* srow = S + (long)blockIdx.x * 2048;
    const int t = threadIdx.x;
    const int lane = t & 63;
    const int wave = t >> 6;

    f32x4 v0 = *reinterpret_cast<const f32x4*>(srow + t * 4);
    f32x4 v1 = *reinterpret_cast<const f32x4*>(srow + 1024 + t * 4);

    float m = v0[0];
#pragma unroll
    for (int i = 1; i < 4; ++i) m = fmaxf(m, v0[i]);
#pragma unroll
    for (int i = 0; i < 4; ++i) m = fmaxf(m, v1[i]);
#pragma unroll
    for (int off = 32; off > 0; off >>= 1) m = fmaxf(m, __shfl_xor(m, off));
    if (lane == 0) redm[wave] = m;
    __syncthreads();
    m = fmaxf(fmaxf(redm[0], redm[1]), fmaxf(redm[2], redm[3]));

    float s = 0.f;
#pragma unroll
    for (int i = 0; i < 4; ++i) { v0[i] = __expf(v0[i] - m); s += v0[i]; }
#pragma unroll
    for (int i = 0; i < 4; ++i) { v1[i] = __expf(v1[i] - m); s += v1[i]; }
#pragma unroll
    for (int off = 32; off > 0; off >>= 1) s += __shfl_xor(s, off);
    if (lane == 0) reds[wave] = s;
    __syncthreads();
    s = reds[0] + reds[1] + reds[2] + reds[3];
    float inv = 1.f / s;

    bf16x4 h0, h1, l0, l1;
#pragma unroll
    for (int i = 0; i < 4; ++i) {
        float a = v0[i] * inv, b = v1[i] * inv;
        h0[i] = (bf16)a; l0[i] = (bf16)(a - (float)h0[i]);
        h1[i] = (bf16)b; l1[i] = (bf16)(b - (float)h1[i]);
    }
    bf16* ph = (bf16*)srow;
    *reinterpret_cast<bf16x4*>(ph + t * 4) = h0;
    *reinterpret_cast<bf16x4*>(ph + 1024 + t * 4) = h1;
    *reinterpret_cast<bf16x4*>(ph + 2048 + t * 4) = l0;
    *reinterpret_cast<bf16x4*>(ph + 3072 + t * 4) = l1;
}

// f32[n] -> hi bf16 at hi[i], lo bf16 at lo[i]. n % 1024 == 0.
__global__ __launch_bounds__(256) void split2_f32(
    const float* __restrict__ in, bf16* __restrict__ hi, bf16* __restrict__ lo)
{
    long i = ((long)blockIdx.x * 256 + threadIdx.x) * 4;
    f32x4 v = *reinterpret_cast<const f32x4*>(in + i);
    bf16x4 h, l;
#pragma unroll
    for (int j = 0; j < 4; ++j) {
        h[j] = (bf16)v[j];
        l[j] = (bf16)(v[j] - (float)h[j]);
    }
    *reinterpret_cast<bf16x4*>(hi + i) = h;
    *reinterpret_cast<bf16x4*>(lo + i) = l;
}

extern "C" void kernel_launch(void* const* d_in, const int* in_sizes, int n_in,
                              void* d_out, int out_size, void* d_ws, size_t ws_size,
                              hipStream_t stream)
{
    const float* x   = (const float*)d_in[0];
    const float* y   = (const float*)d_in[1];
    const float* Wq1 = (const float*)d_in[2];
    const float* bq1 = (const float*)d_in[3];
    const float* Wk1 = (const float*)d_in[4];
    const float* bk1 = (const float*)d_in[5];
    const float* Wv1 = (const float*)d_in[6];
    const float* bv1 = (const float*)d_in[7];
    const float* Wq2 = (const float*)d_in[8];
    const float* bq2 = (const float*)d_in[9];
    const float* Wk2 = (const float*)d_in[10];
    const float* bk2 = (const float*)d_in[11];
    const float* Wv2 = (const float*)d_in[12];
    const float* bv2 = (const float*)d_in[13];
    const float* w1  = (const float*)d_in[14];
    const float* w2  = (const float*)d_in[15];
    float* out = (float*)d_out;

    const size_t MB = 1ull << 20;
    char* ws = (char*)d_ws;
    const long S = 2048, M4 = 8192, E1 = 512, E2 = 1024;
    const long W1ps = E1 * E1, W2ps = E2 * E2;

    const int cfg = (ws_size >= 207 * MB) ? 2 : 0;

    auto gemm = [&](const bf16* A, long lda, long psA, long bsA,
                    const bf16* B, long ldb, long psB, long bsB,
                    void* C, long ldc, long psC, long bsC, int mode,
                    const float* bias, const float* bias2, int nsplit,
                    const float* resid, long ldr, long bsR,
                    const float* scale, int M, int N, int K, int split, int gz) {
        int nx = N / 128, ny = M / 128;
        dim3 g((unsigned)(nx * ny * gz));
        gemm_split<<<g, dim3(256), 0, stream>>>(
            A, lda, psA, bsA, B, ldb, psB, bsB, C, ldc, psC, bsC, mode,
            bias, bias2, nsplit, resid, ldr, bsR, scale, K, split, nx, ny);
    };
    auto scores256 = [&](const bf16* A, long lda, long psA, long bsA,
                         const bf16* B, long ldb, long psB, long bsB,
                         float* C, int K) {
        gemm256_scores<<<dim3(256), dim3(512), 0, stream>>>(
            A, lda, psA, bsA, B, ldb, psB, bsB, C, S, S * S, K);
    };
    auto conv2 = [&](const float* in, bf16* hi, bf16* lo, long n) {
        split2_f32<<<dim3((unsigned)(n / 1024)), dim3(256), 0, stream>>>(in, hi, lo);
    };

    if (cfg == 2) {
        // --- buffers ---
        bf16* xyp   = (bf16*)d_out;            // [2][16384][512]: rows 0-8191 x, 8192+ y (32MB)
        bf16* Wqk1p = (bf16*)(ws + 0 * MB);    // [2][1024][512] stacked Q|K (2MB)
        bf16* Wv1p  = (bf16*)(ws + 2 * MB);    // [2][512][512] (1MB)
        bf16* Wqk2p = (bf16*)(ws + 3 * MB);    // [2][2048][1024] stacked Q|K (8MB)
        bf16* Wv2p  = (bf16*)(ws + 11 * MB);   // [2][1024][1024] (4MB)
        bf16* temp  = (bf16*)(ws + 15 * MB);   // [2][8192][1024] (32MB)
        bf16* qk    = (bf16*)(ws + 47 * MB);   // stage1: [2][16384][1024]; stage2: [2][8192][2048] (64MB)
        bf16* vt    = (bf16*)(ws + 111 * MB);  // stage1: [8][2][512][2048]; stage2: [4][2][1024][2048] (32MB)
        float* Sc   = (float*)(ws + 143 * MB); // [4][2048][2048] f32 (64MB)

        const long PXY = 16384L * 512;         // xyp plane
        const long PW1 = 1024L * 512;          // Wqk1 plane
        const long PW2 = 2048L * 1024;         // Wqk2 plane
        const long PQ1 = 16384L * 1024;        // stage1 qk plane
        const long PQ2 = 8192L * 2048;         // stage2 qk plane (same bytes)
        const long PT  = 8192L * 1024;         // temp plane
        const long BV1 = 2 * E1 * S;           // vt batch stride stage1
        const long BV2 = 2 * E2 * S;           // stage2

        // --- split inputs & weights ---
        conv2(x, xyp, xyp + PXY, M4 * E1);
        conv2(y, xyp + M4 * E1, xyp + PXY + M4 * E1, M4 * E1);
        conv2(Wq1, Wqk1p, Wqk1p + PW1, W1ps);
        conv2(Wk1, Wqk1p + W1ps, Wqk1p + PW1 + W1ps, W1ps);
        conv2(Wv1, Wv1p, Wv1p + W1ps, W1ps);
        conv2(Wq2, Wqk2p, Wqk2p + PW2, W2ps);
        conv2(Wk2, Wqk2p + W2ps, Wqk2p + PW2 + W2ps, W2ps);
        conv2(Wv2, Wv2p, Wv2p + W2ps, W2ps);

        // --- stage 1: batched projections (x|y rows, Q|K cols) ---
        gemm(xyp, E1, PXY, 0, Wqk1p, E1, PW1, 0,
             qk, 1024, PQ1, 0, 1, bq1, bk1, 512,
             nullptr, 0, 0, nullptr, 16384, 1024, 512, 3, 1);
        gemm(xyp, E1, PXY, 0, Wv1p, E1, W1ps, 0,
             vt, S, E1 * S, BV1, 2, bv1, nullptr, 512,
             nullptr, 0, 0, nullptr, 16384, 512, 512, 3, 1);

        // --- x path: scores -> softmax -> PV (+ y*w2) -> temp cols 0-511 ---
        scores256(qk, 1024, PQ1, S * 1024, qk + 512, 1024, PQ1, S * 1024, Sc, 512);
        softmax_planes<<<dim3(8192), dim3(256), 0, stream>>>(Sc);
        gemm((const bf16*)Sc, 4096, 2048, S * 4096, vt, S, E1 * S, BV1,
             temp, 1024, PT, S * 1024, 1, nullptr, nullptr, 512,
             y, E1, S * E1, w2, 2048, 512, 2048, 3, 4);

        // --- y path ---
        scores256(qk + M4 * 1024, 1024, PQ1, S * 1024,
                  qk + M4 * 1024 + 512, 1024, PQ1, S * 1024, Sc, 512);
        softmax_planes<<<dim3(8192), dim3(256), 0, stream>>>(Sc);
        gemm((const bf16*)Sc, 4096, 2048, S * 4096, vt + 4 * BV1, S, E1 * S, BV1,
             temp + 512, 1024, PT, S * 1024, 1, nullptr, nullptr, 512,
             x, E1, S * E1, w1, 2048, 512, 2048, 3, 4);

        // --- stage 2 ---
        gemm(temp, E2, PT, 0, Wqk2p, E2, PW2, 0,
             qk, 2048, PQ2, 0, 1, bq2, bk2, 1024,
             nullptr, 0, 0, nullptr, 8192, 2048, 1024, 3, 1);
        gemm(temp, E2, PT, 0, Wv2p, E2, W2ps, 0,
             vt, S, E2 * S, BV2, 2, bv2, nullptr, 1024,
             nullptr, 0, 0, nullptr, 8192, 1024, 1024, 1, 1);
        scores256(qk, 2048, PQ2, S * 2048, qk + 1024, 2048, PQ2, S * 2048, Sc, 1024);
        softmax_planes<<<dim3(8192), dim3(256), 0, stream>>>(Sc);
        gemm((const bf16*)Sc, 4096, 2048, S * 4096, vt, S, E2 * S, BV2,
             out, E2, 0, S * E2, 0, nullptr, nullptr, 1024,
             nullptr, 0, 0, nullptr, 2048, 1024, 2048, 1, 4);
    } else {
        // --- legacy small-workspace path (original layout, per-batch loops) ---
        bf16* xp = (bf16*)d_out;
        bf16* yp = xp + 2 * M4 * E1;
        bf16* Wq1p = (bf16*)(ws + 0 * MB);
        bf16* Wk1p = (bf16*)(ws + 1 * MB);
        bf16* Wv1p = (bf16*)(ws + 2 * MB);
        bf16* temp = (bf16*)(ws + 3 * MB);
        bf16* qb   = (bf16*)(ws + 35 * MB);
        bf16* kb   = (bf16*)(ws + 43 * MB);
        bf16* vt   = (bf16*)(ws + 51 * MB);
        float* Sc  = (float*)(ws + 59 * MB);
        bf16* Wq2p = (bf16*)d_out;
        bf16* Wk2p = Wq2p + 2 * W2ps;
        bf16* Wv2p = Wk2p + 2 * W2ps;

        conv2(x, xp, xp + M4 * E1, M4 * E1);
        conv2(y, yp, yp + M4 * E1, M4 * E1);
        conv2(Wq1, Wq1p, Wq1p + W1ps, W1ps);
        conv2(Wk1, Wk1p, Wk1p + W1ps, W1ps);
        conv2(Wv1, Wv1p, Wv1p + W1ps, W1ps);

        auto stage1 = [&](const bf16* sp, const float* resid, const float* scale, long colOff) {
            for (int b = 0; b < 4; ++b) {
                const bf16* sb = sp + (long)b * S * E1;
                gemm(sb, E1, M4 * E1, 0, Wq1p, E1, W1ps, 0, qb, E1, S * E1, 0, 1,
                     bq1, nullptr, 512, nullptr, 0, 0, nullptr, 2048, 512, 512, 3, 1);
                gemm(sb, E1, M4 * E1, 0, Wk1p, E1, W1ps, 0, kb, E1, S * E1, 0, 1,
                     bk1, nullptr, 512, nullptr, 0, 0, nullptr, 2048, 512, 512, 3, 1);
                gemm(sb, E1, M4 * E1, 0, Wv1p, E1, W1ps, 0, vt, S, E1 * S, 0, 2,
                     bv1, nullptr, 512, nullptr, 0, 0, nullptr, 2048, 512, 512, 3, 1);
                gemm(qb, E1, S * E1, 0, kb, E1, S * E1, 0, Sc, S, 0, 0, 0,
                     nullptr, nullptr, 2048, nullptr, 0, 0, nullptr, 2048, 2048, 512, 3, 1);
                softmax_planes<<<dim3(2048), dim3(256), 0, stream>>>(Sc);
                gemm((const bf16*)Sc, 4096, 2048, 0, vt, S, E1 * S, 0,
                     temp + colOff + (long)b * S * 1024, 1024, M4 * 1024, 0, 1,
                     nullptr, nullptr, 512, resid + (long)b * S * E1, E1, 0, scale,
                     2048, 512, 2048, 3, 1);
            }
        };

        stage1(xp, y, w2, 0);
        stage1(yp, x, w1, 512);

        conv2(Wq2, Wq2p, Wq2p + W2ps, W2ps);
        conv2(Wk2, Wk2p, Wk2p + W2ps, W2ps);
        conv2(Wv2, Wv2p, Wv2p + W2ps, W2ps);

        for (int b = 0; b < 4; ++b) {
            const bf16* tb = temp + (long)b * S * E2;
            gemm(tb, E2, M4 * E2, 0, Wq2p, E2, W2ps, 0, qb, E2, S * E2, 0, 1,
                 bq2, nullptr, 1024, nullptr, 0, 0, nullptr, 2048, 1024, 1024, 3, 1);
            gemm(tb, E2, M4 * E2, 0, Wk2p, E2, W2ps, 0, kb, E2, S * E2, 0, 1,
                 bk2, nullptr, 1024, nullptr, 0, 0, nullptr, 2048, 1024, 1024, 3, 1);
            gemm(tb, E2, M4 * E2, 0, Wv2p, E2, W2ps, 0, vt, S, E2 * S, 0, 2,
                 bv2, nullptr, 1024, nullptr, 0, 0, nullptr, 2048, 1024, 1024, 1, 1);
            gemm(qb, E2, S * E2, 0, kb, E2, S * E2, 0, Sc, S, 0, 0, 0,
                 nullptr, nullptr, 2048, nullptr, 0, 0, nullptr, 2048, 2048, 1024, 3, 1);
            softmax_planes<<<dim3(2048), dim3(256), 0, stream>>>(Sc);
            gemm((const bf16*)Sc, 4096, 2048, 0, vt, S, E2 * S, 0,
                 out + (long)b * S * E2, E2, 0, 0, 0, nullptr, nullptr, 1024,
                 nullptr, 0, 0, nullptr, 2048, 1024, 2048, 1, 1);
        }
    }

    (void)in_sizes; (void)n_in; (void)out_size;
}

// Round 6
// 906.104 us; speedup vs baseline: 1.0522x; 1.0522x over previous
//
#include <hip/hip_runtime.h>
#include <hip/hip_bf16.h>
#include <cstdint>
#include <cstddef>

// Cross_attention_dl: B=4, S=2048, D1=512, D2=1024. ALL I/O f32.
// Split-precision (bf16 hi/lo plane) MFMA pipeline; operands pre-split in
// global. Round 14: (a) REVERT round-13's gemm_split restructure (regressed
// 920->953: at 2 blocks/CU the old loop was already TLP-hidden, and the
// split-MFMA/sched_barrier form lengthened the barrier convoy); (b) the two
// batched Q|K projections (exact 256-block grids at 256^2 tiles: QK1 64x4,
// QK2 32x8) move to the 256^2 8-wave structure via gemm256 = generalized
// gemm256_scores (general nx/ny/gz decode + mode-1 bf16 plane-pair epilogue
// with dual bias). K-tile order and per-element MFMA accumulation sequence
// identical -> absmax unchanged.

typedef __bf16 bf16;
typedef __attribute__((ext_vector_type(8))) __bf16 bf16x8;
typedef __attribute__((ext_vector_type(4))) __bf16 bf16x4;
typedef __attribute__((ext_vector_type(4))) float f32x4;

__device__ __forceinline__ void gld16(const bf16* g, bf16* s) {
    __builtin_amdgcn_global_load_lds(
        (const __attribute__((address_space(1))) void*)g,
        (__attribute__((address_space(3))) void*)s, 16, 0, 0);
}

// gfx9 waitcnt imm: vmcnt[3:0]+[15:14], expcnt[6:4], lgkmcnt[11:8]
#define WAIT_VM8   __builtin_amdgcn_s_waitcnt(8 | (7 << 4) | (0xF << 8))
#define WAIT_VM0   __builtin_amdgcn_s_waitcnt(0 | (7 << 4) | (0xF << 8))
#define WAIT_LGKM0 __builtin_amdgcn_s_waitcnt(0xF | (7 << 4) | (0 << 8) | (3 << 14))

// element offset of logical (row, col-group g) in a swizzled [rows][64] tile
__device__ __forceinline__ int swz(int row, int g) {
    return row * 64 + ((g ^ (row & 7)) << 3);
}

// ---------------------------------------------------------------------------
// 128^2-tile kernel (round-12 body): V projections / PV / cfg==0 paths.
// C = A @ B^T over bf16 planes. All strides in ELEMENTS. Flat 1-D grid with
// XCD supertile decode. Requires grid % 128 == 0.
// split=3: phases (A0,B0),(A1,B0),(A0,B1); split=1: (A0,B0) only.
// bias: col gcol < nsplit -> bias[gcol], else bias2[gcol-nsplit].
// mode 0: f32 C[z][m][n] = acc (+resid*scale)
// mode 1: bf16 plane-pair row-major: C[p][z*M+m][n] = acc + bias (+resid*scale)
// mode 2: bf16 plane-pair transposed: C[b][p][n][s] (b=grow>>11, s=grow&2047)
__global__ __launch_bounds__(256) void gemm_split(
    const bf16* __restrict__ A, long lda, long psA, long bsA,
    const bf16* __restrict__ B, long ldb, long psB, long bsB,
    void* __restrict__ C, long ldc, long psC, long bsC, int mode,
    const float* __restrict__ bias, const float* __restrict__ bias2, int nsplit,
    const float* __restrict__ resid, long ldr, long bsR,
    const float* __restrict__ scale,
    int K, int split, int nx, int ny)
{
    __shared__ __align__(16) bf16 As[2][128 * 64];
    __shared__ __align__(16) bf16 Bs[2][128 * 64];

    const int t    = threadIdx.x;
    const int wave = t >> 6;
    const int lane = t & 63;
    const int wr   = wave >> 1;
    const int wc   = wave & 1;
    const int r16  = lane & 15;
    const int quad = lane >> 4;

    const int g    = blockIdx.x;
    const int xcd  = g & 7;
    const int tk   = g >> 3;
    const int nst8 = gridDim.x >> 7;              // supertiles per XCD
    const int st   = xcd * nst8 + (tk >> 4);      // global supertile id
    const int p    = tk & 15;                     // position in 4x4 supertile
    const int snx  = nx >> 2, sny = ny >> 2;
    const int spz  = snx * sny;
    const int zz   = st / spz;
    const int rS   = st - zz * spz;
    const int sy   = rS / snx;
    const int sx   = rS - sy * snx;
    const int yb   = sy * 4 + (p >> 2);
    const int xb   = sx * 4 + (p & 3);
    const long z   = zz;

    const long row0 = (long)yb * 128;
    const long col0 = (long)xb * 128;

    const int srow = (lane >> 3);                  // 0..7 within an 8-row chunk
    const int scol = ((lane & 7) ^ srow) * 8;      // swizzled col group this lane fetches

    const int ktiles = K >> 6;
    const int T = split * ktiles;

    const bf16* Az = A + z * bsA;
    const bf16* Bz = B + z * bsB;

    auto prefetch = [&](int ti, int buf) {
        const int ph = ti / ktiles;
        const int kt = (ti - ph * ktiles) << 6;
        const bf16* Ab = Az + (ph == 1 ? psA : 0);
        const bf16* Bb = Bz + (ph == 2 ? psB : 0);
#pragma unroll
        for (int p2 = 0; p2 < 4; ++p2) {
            const int chunk = wave * 32 + p2 * 8;   // 8 rows per 1KB wave store
            gld16(Ab + (row0 + chunk + srow) * lda + kt + scol, &As[buf][chunk * 64]);
            gld16(Bb + (col0 + chunk + srow) * ldb + kt + scol, &Bs[buf][chunk * 64]);
        }
    };

    f32x4 acc[4][4];
#pragma unroll
    for (int r = 0; r < 4; ++r)
#pragma unroll
        for (int c = 0; c < 4; ++c)
            acc[r][c] = (f32x4){0.f, 0.f, 0.f, 0.f};

    prefetch(0, 0);
    prefetch(1, 1);
    for (int ti = 0; ti < T; ++ti) {
        const int cur = ti & 1;
        if (ti + 1 < T) WAIT_VM8; else WAIT_VM0;   // oldest 8 (cur tile) landed
        __builtin_amdgcn_s_barrier();
        bf16x8 af[2][4], bg[2][4];
#pragma unroll
        for (int kk = 0; kk < 2; ++kk) {
            const int g0 = (kk << 2) + quad;
#pragma unroll
            for (int r = 0; r < 4; ++r)
                af[kk][r] = *reinterpret_cast<const bf16x8*>(&As[cur][swz(wr * 64 + r * 16 + r16, g0)]);
#pragma unroll
            for (int c = 0; c < 4; ++c)
                bg[kk][c] = *reinterpret_cast<const bf16x8*>(&Bs[cur][swz(wc * 64 + c * 16 + r16, g0)]);
        }
        WAIT_LGKM0;                                 // frags in regs
        __builtin_amdgcn_s_barrier();               // cur buffer free
        if (ti + 2 < T) prefetch(ti + 2, cur);
#pragma unroll
        for (int kk = 0; kk < 2; ++kk)
#pragma unroll
            for (int r = 0; r < 4; ++r)
#pragma unroll
                for (int c = 0; c < 4; ++c)
                    acc[r][c] = __builtin_amdgcn_mfma_f32_16x16x32_bf16(af[kk][r], bg[kk][c], acc[r][c], 0, 0, 0);
    }

    const float scv = resid ? *scale : 0.f;

#pragma unroll
    for (int r = 0; r < 4; ++r) {
#pragma unroll
        for (int c = 0; c < 4; ++c) {
            long gcol = col0 + wc * 64 + c * 16 + r16;
            float bv = 0.f;
            if (bias) bv = (gcol < nsplit) ? bias[gcol] : bias2[gcol - nsplit];
#pragma unroll
            for (int i = 0; i < 4; ++i) {
                long grow = row0 + wr * 64 + r * 16 + quad * 4 + i;
                float val = acc[r][c][i] + bv;
                if (mode == 0) {
                    if (resid) val += resid[z * bsR + grow * ldr + gcol] * scv;
                    ((float*)C)[z * bsC + grow * ldc + gcol] = val;
                } else if (mode == 1) {
                    if (resid) val += resid[z * bsR + grow * ldr + gcol] * scv;
                    bf16* Cb = (bf16*)C + z * bsC;
                    bf16 h = (bf16)val;
                    Cb[grow * ldc + gcol] = h;
                    Cb[psC + grow * ldc + gcol] = (bf16)(val - (float)h);
                } else {
                    long b = grow >> 11, s = grow & 2047;
                    bf16* Cb = (bf16*)C + b * bsC;
                    bf16 h = (bf16)val;
                    Cb[gcol * ldc + s] = h;
                    Cb[psC + gcol * ldc + s] = (bf16)(val - (float)h);
                }
            }
        }
    }
}

// ---------------------------------------------------------------------------
// 256^2-tile 8-wave kernel: C = A @ B^T, generalized from the scores kernel.
// Grid = nx*ny*gz blocks (must be % 8 == 0; all uses here are exactly 256 =
// 1 block/CU, 128KiB LDS). All 24 ds_read_b128 issued up front in wait-group
// order; MFMA quadrants run under compiler-counted lgkm waits; 2 barriers
// per K-tile; counted vmcnt(8) at top with 2-deep prefetch.
// mode 0: f32 C[z*bsC + m*ldc + n] = acc
// mode 1: bf16 plane-pair row-major + dual bias (nsplit column split)
__global__ __launch_bounds__(512) void gemm256(
    const bf16* __restrict__ A, long lda, long psA, long bsA,
    const bf16* __restrict__ B, long ldb, long psB, long bsB,
    void* __restrict__ C, long ldc, long psC, long bsC, int mode,
    const float* __restrict__ bias, const float* __restrict__ bias2, int nsplit,
    int K, int split, int nx, int ny)
{
    __shared__ __align__(16) bf16 As[2][256 * 64];   // 64 KiB
    __shared__ __align__(16) bf16 Bs[2][256 * 64];   // 64 KiB

    const int t    = threadIdx.x;
    const int wave = t >> 6;          // 0..7
    const int lane = t & 63;
    const int wm   = wave >> 2;       // 0..1 -> 128-row half
    const int wn   = wave & 3;        // 0..3 -> 64-col slice
    const int r16  = lane & 15;
    const int quad = lane >> 4;

    // XCD-contiguous decode: gridDim/8 consecutive tiles per XCD, tx-major
    // within a row of tiles (consecutive tiles share the A-strip -> L2 reuse).
    const int g     = blockIdx.x;
    const int chunk = gridDim.x >> 3;
    const int idx   = (g & 7) * chunk + (g >> 3);
    const int tpz   = nx * ny;
    const int z     = idx / tpz;
    const int r0i   = idx - z * tpz;
    const int ty    = r0i / nx;
    const int tx    = r0i - ty * nx;
    const long row0 = (long)ty * 256;
    const long col0 = (long)tx * 256;

    const int srow = lane >> 3;                    // 0..7 in an 8-row chunk
    const int scol = ((lane & 7) ^ srow) * 8;      // pre-swizzled source group

    const int ktiles = K >> 6;
    const int T = split * ktiles;

    const bf16* Az = A + (long)z * bsA;
    const bf16* Bz = B + (long)z * bsB;

    auto prefetch = [&](int ti, int buf) {
        const int ph = ti / ktiles;
        const int kt = (ti - ph * ktiles) << 6;
        const bf16* Ab = Az + (ph == 1 ? psA : 0);
        const bf16* Bb = Bz + (ph == 2 ? psB : 0);
#pragma unroll
        for (int p2 = 0; p2 < 4; ++p2) {           // wave covers 32 rows of A and B
            const int chnk = wave * 32 + p2 * 8;   // 8 rows per 1KiB wave store
            gld16(Ab + (row0 + chnk + srow) * lda + kt + scol, &As[buf][chnk * 64]);
            gld16(Bb + (col0 + chnk + srow) * ldb + kt + scol, &Bs[buf][chnk * 64]);
        }
    };

    f32x4 acc[8][4];
#pragma unroll
    for (int r = 0; r < 8; ++r)
#pragma unroll
        for (int c = 0; c < 4; ++c)
            acc[r][c] = (f32x4){0.f, 0.f, 0.f, 0.f};

    prefetch(0, 0);
    prefetch(1, 1);
    for (int ti = 0; ti < T; ++ti) {
        const int cur = ti & 1;
        if (ti + 1 < T) WAIT_VM8; else WAIT_VM0;    // oldest 8 (tile ti) landed
        __builtin_amdgcn_s_barrier();

        // Issue ALL fragment reads in wait-group order.
        bf16x8 afA[4][2], afB[4][2], bg[2][2][2];
#pragma unroll
        for (int kk = 0; kk < 2; ++kk) {            // group 1: afA (8 reads)
            const int g0 = (kk << 2) + quad;
#pragma unroll
            for (int r = 0; r < 4; ++r)
                afA[r][kk] = *reinterpret_cast<const bf16x8*>(
                    &As[cur][swz(wm * 128 + r * 16 + r16, g0)]);
        }
#pragma unroll
        for (int kk = 0; kk < 2; ++kk) {            // group 2: bg0 (4 reads)
            const int g0 = (kk << 2) + quad;
#pragma unroll
            for (int c = 0; c < 2; ++c)
                bg[0][c][kk] = *reinterpret_cast<const bf16x8*>(
                    &Bs[cur][swz(wn * 64 + c * 16 + r16, g0)]);
        }
#pragma unroll
        for (int kk = 0; kk < 2; ++kk) {            // group 3: bg1 (4 reads)
            const int g0 = (kk << 2) + quad;
#pragma unroll
            for (int c = 0; c < 2; ++c)
                bg[1][c][kk] = *reinterpret_cast<const bf16x8*>(
                    &Bs[cur][swz(wn * 64 + (2 + c) * 16 + r16, g0)]);
        }
#pragma unroll
        for (int kk = 0; kk < 2; ++kk) {            // group 4: afB (8 reads)
            const int g0 = (kk << 2) + quad;
#pragma unroll
            for (int r = 0; r < 4; ++r)
                afB[r][kk] = *reinterpret_cast<const bf16x8*>(
                    &As[cur][swz(wm * 128 + (4 + r) * 16 + r16, g0)]);
        }

        // Q00/Q01 under counted lgkm waits; bg1/afB drain underneath.
        __builtin_amdgcn_s_setprio(1);
#pragma unroll
        for (int kk = 0; kk < 2; ++kk)
#pragma unroll
            for (int r = 0; r < 4; ++r)
#pragma unroll
                for (int c = 0; c < 2; ++c)
                    acc[r][c] = __builtin_amdgcn_mfma_f32_16x16x32_bf16(
                        afA[r][kk], bg[0][c][kk], acc[r][c], 0, 0, 0);
#pragma unroll
        for (int kk = 0; kk < 2; ++kk)
#pragma unroll
            for (int r = 0; r < 4; ++r)
#pragma unroll
                for (int c = 0; c < 2; ++c)
                    acc[r][2 + c] = __builtin_amdgcn_mfma_f32_16x16x32_bf16(
                        afA[r][kk], bg[1][c][kk], acc[r][2 + c], 0, 0, 0);
        __builtin_amdgcn_s_setprio(0);

        __builtin_amdgcn_sched_barrier(0);          // pin all read issues above
        WAIT_LGKM0;                                 // all 24 reads complete
        __builtin_amdgcn_s_barrier();               // LDS WAR fence: buf[cur] free
        if (ti + 2 < T) prefetch(ti + 2, cur);      // 8 gld16, covered by Q10/Q11

        __builtin_amdgcn_s_setprio(1);
#pragma unroll
        for (int kk = 0; kk < 2; ++kk)
#pragma unroll
            for (int r = 0; r < 4; ++r)
#pragma unroll
                for (int c = 0; c < 2; ++c)
                    acc[4 + r][c] = __builtin_amdgcn_mfma_f32_16x16x32_bf16(
                        afB[r][kk], bg[0][c][kk], acc[4 + r][c], 0, 0, 0);
#pragma unroll
        for (int kk = 0; kk < 2; ++kk)
#pragma unroll
            for (int r = 0; r < 4; ++r)
#pragma unroll
                for (int c = 0; c < 2; ++c)
                    acc[4 + r][2 + c] = __builtin_amdgcn_mfma_f32_16x16x32_bf16(
                        afB[r][kk], bg[1][c][kk], acc[4 + r][2 + c], 0, 0, 0);
        __builtin_amdgcn_s_setprio(0);
    }

#pragma unroll
    for (int r = 0; r < 8; ++r) {
#pragma unroll
        for (int c = 0; c < 4; ++c) {
            const long gcol = col0 + wn * 64 + c * 16 + r16;
            float bv = 0.f;
            if (bias) bv = (gcol < nsplit) ? bias[gcol] : bias2[gcol - nsplit];
#pragma unroll
            for (int i = 0; i < 4; ++i) {
                const long grow = row0 + wm * 128 + r * 16 + quad * 4 + i;
                float val = acc[r][c][i] + bv;
                if (mode == 0) {
                    ((float*)C)[(long)z * bsC + grow * ldc + gcol] = val;
                } else {
                    bf16* Cb = (bf16*)C + (long)z * bsC;
                    bf16 h = (bf16)val;
                    Cb[grow * ldc + gcol] = h;
                    Cb[psC + grow * ldc + gcol] = (bf16)(val - (float)h);
                }
            }
        }
    }
}

// Row softmax over 2048 f32 cols; writes P IN PLACE as bf16 hi plane (cols
// [0,2048) of the row's 4096 bf16 slots) and lo plane (cols [2048,4096)).
__global__ __launch_bounds__(256) void softmax_planes(float* __restrict__ S)
{
    __shared__ float redm[4], reds[4];
    float* srow = S + (long)blockIdx.x * 2048;
    const int t = threadIdx.x;
    const int lane = t & 63;
    const int wave = t >> 6;

    f32x4 v0 = *reinterpret_cast<const f32x4*>(srow + t * 4);
    f32x4 v1 = *reinterpret_cast<const f32x4*>(srow + 1024 + t * 4);

    float m = v0[0];
#pragma unroll
    for (int i = 1; i < 4; ++i) m = fmaxf(m, v0[i]);
#pragma unroll
    for (int i = 0; i < 4; ++i) m = fmaxf(m, v1[i]);
#pragma unroll
    for (int off = 32; off > 0; off >>= 1) m = fmaxf(m, __shfl_xor(m, off));
    if (lane == 0) redm[wave] = m;
    __syncthreads();
    m = fmaxf(fmaxf(redm[0], redm[1]), fmaxf(redm[2], redm[3]));

    float s = 0.f;
#pragma unroll
    for (int i = 0; i < 4; ++i) { v0[i] = __expf(v0[i] - m); s += v0[i]; }
#pragma unroll
    for (int i = 0; i < 4; ++i) { v1[i] = __expf(v1[i] - m); s += v1[i]; }
#pragma unroll
    for (int off = 32; off > 0; off >>= 1) s += __shfl_xor(s, off);
    if (lane == 0) reds[wave] = s;
    __syncthreads();
    s = reds[0] + reds[1] + reds[2] + reds[3];
    float inv = 1.f / s;

    bf16x4 h0, h1, l0, l1;
#pragma unroll
    for (int i = 0; i < 4; ++i) {
        float a = v0[i] * inv, b = v1[i] * inv;
        h0[i] = (bf16)a; l0[i] = (bf16)(a - (float)h0[i]);
        h1[i] = (bf16)b; l1[i] = (bf16)(b - (float)h1[i]);
    }
    bf16* ph = (bf16*)srow;
    *reinterpret_cast<bf16x4*>(ph + t * 4) = h0;
    *reinterpret_cast<bf16x4*>(ph + 1024 + t * 4) = h1;
    *reinterpret_cast<bf16x4*>(ph + 2048 + t * 4) = l0;
    *reinterpret_cast<bf16x4*>(ph + 3072 + t * 4) = l1;
}

// f32[n] -> hi bf16 at hi[i], lo bf16 at lo[i]. n % 1024 == 0.
__global__ __launch_bounds__(256) void split2_f32(
    const float* __restrict__ in, bf16* __restrict__ hi, bf16* __restrict__ lo)
{
    long i = ((long)blockIdx.x * 256 + threadIdx.x) * 4;
    f32x4 v = *reinterpret_cast<const f32x4*>(in + i);
    bf16x4 h, l;
#pragma unroll
    for (int j = 0; j < 4; ++j) {
        h[j] = (bf16)v[j];
        l[j] = (bf16)(v[j] - (float)h[j]);
    }
    *reinterpret_cast<bf16x4*>(hi + i) = h;
    *reinterpret_cast<bf16x4*>(lo + i) = l;
}

extern "C" void kernel_launch(void* const* d_in, const int* in_sizes, int n_in,
                              void* d_out, int out_size, void* d_ws, size_t ws_size,
                              hipStream_t stream)
{
    const float* x   = (const float*)d_in[0];
    const float* y   = (const float*)d_in[1];
    const float* Wq1 = (const float*)d_in[2];
    const float* bq1 = (const float*)d_in[3];
    const float* Wk1 = (const float*)d_in[4];
    const float* bk1 = (const float*)d_in[5];
    const float* Wv1 = (const float*)d_in[6];
    const float* bv1 = (const float*)d_in[7];
    const float* Wq2 = (const float*)d_in[8];
    const float* bq2 = (const float*)d_in[9];
    const float* Wk2 = (const float*)d_in[10];
    const float* bk2 = (const float*)d_in[11];
    const float* Wv2 = (const float*)d_in[12];
    const float* bv2 = (const float*)d_in[13];
    const float* w1  = (const float*)d_in[14];
    const float* w2  = (const float*)d_in[15];
    float* out = (float*)d_out;

    const size_t MB = 1ull << 20;
    char* ws = (char*)d_ws;
    const long S = 2048, M4 = 8192, E1 = 512, E2 = 1024;
    const long W1ps = E1 * E1, W2ps = E2 * E2;

    const int cfg = (ws_size >= 207 * MB) ? 2 : 0;

    auto gemm = [&](const bf16* A, long lda, long psA, long bsA,
                    const bf16* B, long ldb, long psB, long bsB,
                    void* C, long ldc, long psC, long bsC, int mode,
                    const float* bias, const float* bias2, int nsplit,
                    const float* resid, long ldr, long bsR,
                    const float* scale, int M, int N, int K, int split, int gz) {
        int nx = N / 128, ny = M / 128;
        dim3 g((unsigned)(nx * ny * gz));
        gemm_split<<<g, dim3(256), 0, stream>>>(
            A, lda, psA, bsA, B, ldb, psB, bsB, C, ldc, psC, bsC, mode,
            bias, bias2, nsplit, resid, ldr, bsR, scale, K, split, nx, ny);
    };
    auto g256 = [&](const bf16* A, long lda, long psA, long bsA,
                    const bf16* B, long ldb, long psB, long bsB,
                    void* C, long ldc, long psC, long bsC, int mode,
                    const float* bias, const float* bias2, int nsplit,
                    int K, int split, int M, int N, int gz) {
        int nx = N / 256, ny = M / 256;
        gemm256<<<dim3((unsigned)(nx * ny * gz)), dim3(512), 0, stream>>>(
            A, lda, psA, bsA, B, ldb, psB, bsB, C, ldc, psC, bsC, mode,
            bias, bias2, nsplit, K, split, nx, ny);
    };
    auto conv2 = [&](const float* in, bf16* hi, bf16* lo, long n) {
        split2_f32<<<dim3((unsigned)(n / 1024)), dim3(256), 0, stream>>>(in, hi, lo);
    };

    if (cfg == 2) {
        // --- buffers ---
        bf16* xyp   = (bf16*)d_out;            // [2][16384][512]: rows 0-8191 x, 8192+ y (32MB)
        bf16* Wqk1p = (bf16*)(ws + 0 * MB);    // [2][1024][512] stacked Q|K (2MB)
        bf16* Wv1p  = (bf16*)(ws + 2 * MB);    // [2][512][512] (1MB)
        bf16* Wqk2p = (bf16*)(ws + 3 * MB);    // [2][2048][1024] stacked Q|K (8MB)
        bf16* Wv2p  = (bf16*)(ws + 11 * MB);   // [2][1024][1024] (4MB)
        bf16* temp  = (bf16*)(ws + 15 * MB);   // [2][8192][1024] (32MB)
        bf16* qk    = (bf16*)(ws + 47 * MB);   // stage1: [2][16384][1024]; stage2: [2][8192][2048] (64MB)
        bf16* vt    = (bf16*)(ws + 111 * MB);  // stage1: [8][2][512][2048]; stage2: [4][2][1024][2048] (32MB)
        float* Sc   = (float*)(ws + 143 * MB); // [4][2048][2048] f32 (64MB)

        const long PXY = 16384L * 512;         // xyp plane
        const long PW1 = 1024L * 512;          // Wqk1 plane
        const long PW2 = 2048L * 1024;         // Wqk2 plane
        const long PQ1 = 16384L * 1024;        // stage1 qk plane
        const long PQ2 = 8192L * 2048;         // stage2 qk plane (same bytes)
        const long PT  = 8192L * 1024;         // temp plane
        const long BV1 = 2 * E1 * S;           // vt batch stride stage1
        const long BV2 = 2 * E2 * S;           // stage2

        // --- split inputs & weights ---
        conv2(x, xyp, xyp + PXY, M4 * E1);
        conv2(y, xyp + M4 * E1, xyp + PXY + M4 * E1, M4 * E1);
        conv2(Wq1, Wqk1p, Wqk1p + PW1, W1ps);
        conv2(Wk1, Wqk1p + W1ps, Wqk1p + PW1 + W1ps, W1ps);
        conv2(Wv1, Wv1p, Wv1p + W1ps, W1ps);
        conv2(Wq2, Wqk2p, Wqk2p + PW2, W2ps);
        conv2(Wk2, Wqk2p + W2ps, Wqk2p + PW2 + W2ps, W2ps);
        conv2(Wv2, Wv2p, Wv2p + W2ps, W2ps);

        // --- stage 1: batched projections (x|y rows, Q|K cols) ---
        // QK1 on the 256^2 structure: 64x4 tiles = 256 blocks exactly.
        g256(xyp, E1, PXY, 0, Wqk1p, E1, PW1, 0,
             qk, 1024, PQ1, 0, 1, bq1, bk1, 512,
             512, 3, 16384, 1024, 1);
        gemm(xyp, E1, PXY, 0, Wv1p, E1, W1ps, 0,
             vt, S, E1 * S, BV1, 2, bv1, nullptr, 512,
             nullptr, 0, 0, nullptr, 16384, 512, 512, 3, 1);

        // --- x path: scores -> softmax -> PV (+ y*w2) -> temp cols 0-511 ---
        g256(qk, 1024, PQ1, S * 1024, qk + 512, 1024, PQ1, S * 1024,
             Sc, S, 0, S * S, 0, nullptr, nullptr, 0, 512, 3, 2048, 2048, 4);
        softmax_planes<<<dim3(8192), dim3(256), 0, stream>>>(Sc);
        gemm((const bf16*)Sc, 4096, 2048, S * 4096, vt, S, E1 * S, BV1,
             temp, 1024, PT, S * 1024, 1, nullptr, nullptr, 512,
             y, E1, S * E1, w2, 2048, 512, 2048, 3, 4);

        // --- y path ---
        g256(qk + M4 * 1024, 1024, PQ1, S * 1024,
             qk + M4 * 1024 + 512, 1024, PQ1, S * 1024,
             Sc, S, 0, S * S, 0, nullptr, nullptr, 0, 512, 3, 2048, 2048, 4);
        softmax_planes<<<dim3(8192), dim3(256), 0, stream>>>(Sc);
        gemm((const bf16*)Sc, 4096, 2048, S * 4096, vt + 4 * BV1, S, E1 * S, BV1,
             temp + 512, 1024, PT, S * 1024, 1, nullptr, nullptr, 512,
             x, E1, S * E1, w1, 2048, 512, 2048, 3, 4);

        // --- stage 2 ---
        // QK2 on the 256^2 structure: 32x8 tiles = 256 blocks exactly.
        g256(temp, E2, PT, 0, Wqk2p, E2, PW2, 0,
             qk, 2048, PQ2, 0, 1, bq2, bk2, 1024,
             1024, 3, 8192, 2048, 1);
        gemm(temp, E2, PT, 0, Wv2p, E2, W2ps, 0,
             vt, S, E2 * S, BV2, 2, bv2, nullptr, 1024,
             nullptr, 0, 0, nullptr, 8192, 1024, 1024, 1, 1);
        g256(qk, 2048, PQ2, S * 2048, qk + 1024, 2048, PQ2, S * 2048,
             Sc, S, 0, S * S, 0, nullptr, nullptr, 0, 1024, 3, 2048, 2048, 4);
        softmax_planes<<<dim3(8192), dim3(256), 0, stream>>>(Sc);
        gemm((const bf16*)Sc, 4096, 2048, S * 4096, vt, S, E2 * S, BV2,
             out, E2, 0, S * E2, 0, nullptr, nullptr, 1024,
             nullptr, 0, 0, nullptr, 2048, 1024, 2048, 1, 4);
    } else {
        // --- legacy small-workspace path (original layout, per-batch loops) ---
        bf16* xp = (bf16*)d_out;
        bf16* yp = xp + 2 * M4 * E1;
        bf16* Wq1p = (bf16*)(ws + 0 * MB);
        bf16* Wk1p = (bf16*)(ws + 1 * MB);
        bf16* Wv1p = (bf16*)(ws + 2 * MB);
        bf16* temp = (bf16*)(ws + 3 * MB);
        bf16* qb   = (bf16*)(ws + 35 * MB);
        bf16* kb   = (bf16*)(ws + 43 * MB);
        bf16* vt   = (bf16*)(ws + 51 * MB);
        float* Sc  = (float*)(ws + 59 * MB);
        bf16* Wq2p = (bf16*)d_out;
        bf16* Wk2p = Wq2p + 2 * W2ps;
        bf16* Wv2p = Wk2p + 2 * W2ps;

        conv2(x, xp, xp + M4 * E1, M4 * E1);
        conv2(y, yp, yp + M4 * E1, M4 * E1);
        conv2(Wq1, Wq1p, Wq1p + W1ps, W1ps);
        conv2(Wk1, Wk1p, Wk1p + W1ps, W1ps);
        conv2(Wv1, Wv1p, Wv1p + W1ps, W1ps);

        auto stage1 = [&](const bf16* sp, const float* resid, const float* scale, long colOff) {
            for (int b = 0; b < 4; ++b) {
                const bf16* sb = sp + (long)b * S * E1;
                gemm(sb, E1, M4 * E1, 0, Wq1p, E1, W1ps, 0, qb, E1, S * E1, 0, 1,
                     bq1, nullptr, 512, nullptr, 0, 0, nullptr, 2048, 512, 512, 3, 1);
                gemm(sb, E1, M4 * E1, 0, Wk1p, E1, W1ps, 0, kb, E1, S * E1, 0, 1,
                     bk1, nullptr, 512, nullptr, 0, 0, nullptr, 2048, 512, 512, 3, 1);
                gemm(sb, E1, M4 * E1, 0, Wv1p, E1, W1ps, 0, vt, S, E1 * S, 0, 2,
                     bv1, nullptr, 512, nullptr, 0, 0, nullptr, 2048, 512, 512, 3, 1);
                gemm(qb, E1, S * E1, 0, kb, E1, S * E1, 0, Sc, S, 0, 0, 0,
                     nullptr, nullptr, 2048, nullptr, 0, 0, nullptr, 2048, 2048, 512, 3, 1);
                softmax_planes<<<dim3(2048), dim3(256), 0, stream>>>(Sc);
                gemm((const bf16*)Sc, 4096, 2048, 0, vt, S, E1 * S, 0,
                     temp + colOff + (long)b * S * 1024, 1024, M4 * 1024, 0, 1,
                     nullptr, nullptr, 512, resid + (long)b * S * E1, E1, 0, scale,
                     2048, 512, 2048, 3, 1);
            }
        };

        stage1(xp, y, w2, 0);
        stage1(yp, x, w1, 512);

        conv2(Wq2, Wq2p, Wq2p + W2ps, W2ps);
        conv2(Wk2, Wk2p, Wk2p + W2ps, W2ps);
        conv2(Wv2, Wv2p, Wv2p + W2ps, W2ps);

        for (int b = 0; b < 4; ++b) {
            const bf16* tb = temp + (long)b * S * E2;
            gemm(tb, E2, M4 * E2, 0, Wq2p, E2, W2ps, 0, qb, E2, S * E2, 0, 1,
                 bq2, nullptr, 1024, nullptr, 0, 0, nullptr, 2048, 1024, 1024, 3, 1);
            gemm(tb, E2, M4 * E2, 0, Wk2p, E2, W2ps, 0, kb, E2, S * E2, 0, 1,
                 bk2, nullptr, 1024, nullptr, 0, 0, nullptr, 2048, 1024, 1024, 3, 1);
            gemm(tb, E2, M4 * E2, 0, Wv2p, E2, W2ps, 0, vt, S, E2 * S, 0, 2,
                 bv2, nullptr, 1024, nullptr, 0, 0, nullptr, 2048, 1024, 1024, 1, 1);
            gemm(qb, E2, S * E2, 0, kb, E2, S * E2, 0, Sc, S, 0, 0, 0,
                 nullptr, nullptr, 2048, nullptr, 0, 0, nullptr, 2048, 2048, 1024, 3, 1);
            softmax_planes<<<dim3(2048), dim3(256), 0, stream>>>(Sc);
            gemm((const bf16*)Sc, 4096, 2048, 0, vt, S, E2 * S, 0,
                 out + (long)b * S * E2, E2, 0, 0, 0, nullptr, nullptr, 1024,
                 nullptr, 0, 0, nullptr, 2048, 1024, 2048, 1, 1);
        }
    }

    (void)in_sizes; (void)n_in; (void)out_size;
}

// Round 8
// 821.392 us; speedup vs baseline: 1.1607x; 1.1031x over previous
//
#include <hip/hip_runtime.h>
#include <hip/hip_bf16.h>
#include <cstdint>
#include <cstddef>

// Cross_attention_dl: B=4, S=2048, D1=512, D2=1024. ALL I/O f32.
// Split-precision (bf16 hi/lo plane) MFMA pipeline; operands pre-split in
// global. Round 15 (resubmit after container infra failure): stage-1 PV
// GEMMs (round-14 top dispatches: 119us, MfmaUtil 17.5%, Occ 10% = 1
// block/CU latency exposure) get split-K=2 -> 512-block dispatches (2
// blocks/CU, cross-block TLP) writing f32 partials into d_out (input planes
// dead by then); reduce_pv sums halves + resid*scale -> bf16 plane-pair
// into temp. gemm_split gains nz (kh = zz/nz, K-col offset kh*K) + mode-3
// partial epilogue; all other calls pass nz=gz -> unchanged.

typedef __bf16 bf16;
typedef __attribute__((ext_vector_type(8))) __bf16 bf16x8;
typedef __attribute__((ext_vector_type(4))) __bf16 bf16x4;
typedef __attribute__((ext_vector_type(4))) float f32x4;

__device__ __forceinline__ void gld16(const bf16* g, bf16* s) {
    __builtin_amdgcn_global_load_lds(
        (const __attribute__((address_space(1))) void*)g,
        (__attribute__((address_space(3))) void*)s, 16, 0, 0);
}

// gfx9 waitcnt imm: vmcnt[3:0]+[15:14], expcnt[6:4], lgkmcnt[11:8]
#define WAIT_VM8   __builtin_amdgcn_s_waitcnt(8 | (7 << 4) | (0xF << 8))
#define WAIT_VM0   __builtin_amdgcn_s_waitcnt(0 | (7 << 4) | (0xF << 8))
#define WAIT_LGKM0 __builtin_amdgcn_s_waitcnt(0xF | (7 << 4) | (0 << 8) | (3 << 14))

// element offset of logical (row, col-group g) in a swizzled [rows][64] tile
__device__ __forceinline__ int swz(int row, int g) {
    return row * 64 + ((g ^ (row & 7)) << 3);
}

// ---------------------------------------------------------------------------
// 128^2-tile kernel: V projections / PV / cfg==0 paths.
// C = A @ B^T over bf16 planes. All strides in ELEMENTS. Flat 1-D grid with
// XCD supertile decode. Requires grid % 128 == 0.
// z-blocks: zz in [0, gz*ksplit); kh = zz/nz selects K-range [kh*K,(kh+1)*K).
// split=3: phases (A0,B0),(A1,B0),(A0,B1); split=1: (A0,B0) only.
// bias: col gcol < nsplit -> bias[gcol], else bias2[gcol-nsplit].
// mode 0: f32 C[z][m][n] = acc (+resid*scale)
// mode 1: bf16 plane-pair row-major: C[p][z*M+m][n] = acc + bias (+resid*scale)
// mode 2: bf16 plane-pair transposed: C[b][p][n][s] (b=grow>>11, s=grow&2047)
// mode 3: f32 partial C[kh*psC + z*bsC + m*ldc + n] = acc (split-K)
__global__ __launch_bounds__(256) void gemm_split(
    const bf16* __restrict__ A, long lda, long psA, long bsA,
    const bf16* __restrict__ B, long ldb, long psB, long bsB,
    void* __restrict__ C, long ldc, long psC, long bsC, int mode,
    const float* __restrict__ bias, const float* __restrict__ bias2, int nsplit,
    const float* __restrict__ resid, long ldr, long bsR,
    const float* __restrict__ scale,
    int K, int split, int nx, int ny, int nz)
{
    __shared__ __align__(16) bf16 As[2][128 * 64];
    __shared__ __align__(16) bf16 Bs[2][128 * 64];

    const int t    = threadIdx.x;
    const int wave = t >> 6;
    const int lane = t & 63;
    const int wr   = wave >> 1;
    const int wc   = wave & 1;
    const int r16  = lane & 15;
    const int quad = lane >> 4;

    const int g    = blockIdx.x;
    const int xcd  = g & 7;
    const int tk   = g >> 3;
    const int nst8 = gridDim.x >> 7;              // supertiles per XCD
    const int st   = xcd * nst8 + (tk >> 4);      // global supertile id
    const int p    = tk & 15;                     // position in 4x4 supertile
    const int snx  = nx >> 2, sny = ny >> 2;
    const int spz  = snx * sny;
    const int zz   = st / spz;
    const int rS   = st - zz * spz;
    const int sy   = rS / snx;
    const int sx   = rS - sy * snx;
    const int yb   = sy * 4 + (p >> 2);
    const int xb   = sx * 4 + (p & 3);

    const int  kh   = zz / nz;                    // split-K half index
    const long z    = zz - (long)kh * nz;
    const long kOff = (long)kh * K;               // K-column offset

    const long row0 = (long)yb * 128;
    const long col0 = (long)xb * 128;

    const int srow = (lane >> 3);                  // 0..7 within an 8-row chunk
    const int scol = ((lane & 7) ^ srow) * 8;      // swizzled col group this lane fetches

    const int ktiles = K >> 6;
    const int T = split * ktiles;

    const bf16* Az = A + z * bsA;
    const bf16* Bz = B + z * bsB;

    auto prefetch = [&](int ti, int buf) {
        const int ph = ti / ktiles;
        const int kt = (ti - ph * ktiles) << 6;
        const bf16* Ab = Az + (ph == 1 ? psA : 0);
        const bf16* Bb = Bz + (ph == 2 ? psB : 0);
#pragma unroll
        for (int p2 = 0; p2 < 4; ++p2) {
            const int chunk = wave * 32 + p2 * 8;   // 8 rows per 1KB wave store
            gld16(Ab + (row0 + chunk + srow) * lda + kt + kOff + scol, &As[buf][chunk * 64]);
            gld16(Bb + (col0 + chunk + srow) * ldb + kt + kOff + scol, &Bs[buf][chunk * 64]);
        }
    };

    f32x4 acc[4][4];
#pragma unroll
    for (int r = 0; r < 4; ++r)
#pragma unroll
        for (int c = 0; c < 4; ++c)
            acc[r][c] = (f32x4){0.f, 0.f, 0.f, 0.f};

    prefetch(0, 0);
    prefetch(1, 1);
    for (int ti = 0; ti < T; ++ti) {
        const int cur = ti & 1;
        if (ti + 1 < T) WAIT_VM8; else WAIT_VM0;   // oldest 8 (cur tile) landed
        __builtin_amdgcn_s_barrier();
        bf16x8 af[2][4], bg[2][4];
#pragma unroll
        for (int kk = 0; kk < 2; ++kk) {
            const int g0 = (kk << 2) + quad;
#pragma unroll
            for (int r = 0; r < 4; ++r)
                af[kk][r] = *reinterpret_cast<const bf16x8*>(&As[cur][swz(wr * 64 + r * 16 + r16, g0)]);
#pragma unroll
            for (int c = 0; c < 4; ++c)
                bg[kk][c] = *reinterpret_cast<const bf16x8*>(&Bs[cur][swz(wc * 64 + c * 16 + r16, g0)]);
        }
        WAIT_LGKM0;                                 // frags in regs
        __builtin_amdgcn_s_barrier();               // cur buffer free
        if (ti + 2 < T) prefetch(ti + 2, cur);
#pragma unroll
        for (int kk = 0; kk < 2; ++kk)
#pragma unroll
            for (int r = 0; r < 4; ++r)
#pragma unroll
                for (int c = 0; c < 4; ++c)
                    acc[r][c] = __builtin_amdgcn_mfma_f32_16x16x32_bf16(af[kk][r], bg[kk][c], acc[r][c], 0, 0, 0);
    }

    const float scv = resid ? *scale : 0.f;

#pragma unroll
    for (int r = 0; r < 4; ++r) {
#pragma unroll
        for (int c = 0; c < 4; ++c) {
            long gcol = col0 + wc * 64 + c * 16 + r16;
            float bv = 0.f;
            if (bias) bv = (gcol < nsplit) ? bias[gcol] : bias2[gcol - nsplit];
#pragma unroll
            for (int i = 0; i < 4; ++i) {
                long grow = row0 + wr * 64 + r * 16 + quad * 4 + i;
                float val = acc[r][c][i] + bv;
                if (mode == 0) {
                    if (resid) val += resid[z * bsR + grow * ldr + gcol] * scv;
                    ((float*)C)[z * bsC + grow * ldc + gcol] = val;
                } else if (mode == 1) {
                    if (resid) val += resid[z * bsR + grow * ldr + gcol] * scv;
                    bf16* Cb = (bf16*)C + z * bsC;
                    bf16 h = (bf16)val;
                    Cb[grow * ldc + gcol] = h;
                    Cb[psC + grow * ldc + gcol] = (bf16)(val - (float)h);
                } else if (mode == 3) {
                    ((float*)C)[(long)kh * psC + z * bsC + grow * ldc + gcol] = val;
                } else {
                    long b = grow >> 11, s = grow & 2047;
                    bf16* Cb = (bf16*)C + b * bsC;
                    bf16 h = (bf16)val;
                    Cb[gcol * ldc + s] = h;
                    Cb[psC + gcol * ldc + s] = (bf16)(val - (float)h);
                }
            }
        }
    }
}

// ---------------------------------------------------------------------------
// 256^2-tile 8-wave kernel: C = A @ B^T. Grid = nx*ny*gz (1 block/CU here).
// All 24 ds_read_b128 issued up front in wait-group order; MFMA quadrants
// run under compiler-counted lgkm waits; 2 barriers per K-tile; counted
// vmcnt(8) at top with 2-deep prefetch.
// mode 0: f32 C[z*bsC + m*ldc + n] = acc
// mode 1: bf16 plane-pair row-major + dual bias (nsplit column split)
__global__ __launch_bounds__(512) void gemm256(
    const bf16* __restrict__ A, long lda, long psA, long bsA,
    const bf16* __restrict__ B, long ldb, long psB, long bsB,
    void* __restrict__ C, long ldc, long psC, long bsC, int mode,
    const float* __restrict__ bias, const float* __restrict__ bias2, int nsplit,
    int K, int split, int nx, int ny)
{
    __shared__ __align__(16) bf16 As[2][256 * 64];   // 64 KiB
    __shared__ __align__(16) bf16 Bs[2][256 * 64];   // 64 KiB

    const int t    = threadIdx.x;
    const int wave = t >> 6;          // 0..7
    const int lane = t & 63;
    const int wm   = wave >> 2;       // 0..1 -> 128-row half
    const int wn   = wave & 3;        // 0..3 -> 64-col slice
    const int r16  = lane & 15;
    const int quad = lane >> 4;

    // XCD-contiguous decode: gridDim/8 consecutive tiles per XCD.
    const int g     = blockIdx.x;
    const int chunk = gridDim.x >> 3;
    const int idx   = (g & 7) * chunk + (g >> 3);
    const int tpz   = nx * ny;
    const int z     = idx / tpz;
    const int r0i   = idx - z * tpz;
    const int ty    = r0i / nx;
    const int tx    = r0i - ty * nx;
    const long row0 = (long)ty * 256;
    const long col0 = (long)tx * 256;

    const int srow = lane >> 3;                    // 0..7 in an 8-row chunk
    const int scol = ((lane & 7) ^ srow) * 8;      // pre-swizzled source group

    const int ktiles = K >> 6;
    const int T = split * ktiles;

    const bf16* Az = A + (long)z * bsA;
    const bf16* Bz = B + (long)z * bsB;

    auto prefetch = [&](int ti, int buf) {
        const int ph = ti / ktiles;
        const int kt = (ti - ph * ktiles) << 6;
        const bf16* Ab = Az + (ph == 1 ? psA : 0);
        const bf16* Bb = Bz + (ph == 2 ? psB : 0);
#pragma unroll
        for (int p2 = 0; p2 < 4; ++p2) {           // wave covers 32 rows of A and B
            const int chnk = wave * 32 + p2 * 8;   // 8 rows per 1KiB wave store
            gld16(Ab + (row0 + chnk + srow) * lda + kt + scol, &As[buf][chnk * 64]);
            gld16(Bb + (col0 + chnk + srow) * ldb + kt + scol, &Bs[buf][chnk * 64]);
        }
    };

    f32x4 acc[8][4];
#pragma unroll
    for (int r = 0; r < 8; ++r)
#pragma unroll
        for (int c = 0; c < 4; ++c)
            acc[r][c] = (f32x4){0.f, 0.f, 0.f, 0.f};

    prefetch(0, 0);
    prefetch(1, 1);
    for (int ti = 0; ti < T; ++ti) {
        const int cur = ti & 1;
        if (ti + 1 < T) WAIT_VM8; else WAIT_VM0;    // oldest 8 (tile ti) landed
        __builtin_amdgcn_s_barrier();

        // Issue ALL fragment reads in wait-group order.
        bf16x8 afA[4][2], afB[4][2], bg[2][2][2];
#pragma unroll
        for (int kk = 0; kk < 2; ++kk) {            // group 1: afA (8 reads)
            const int g0 = (kk << 2) + quad;
#pragma unroll
            for (int r = 0; r < 4; ++r)
                afA[r][kk] = *reinterpret_cast<const bf16x8*>(
                    &As[cur][swz(wm * 128 + r * 16 + r16, g0)]);
        }
#pragma unroll
        for (int kk = 0; kk < 2; ++kk) {            // group 2: bg0 (4 reads)
            const int g0 = (kk << 2) + quad;
#pragma unroll
            for (int c = 0; c < 2; ++c)
                bg[0][c][kk] = *reinterpret_cast<const bf16x8*>(
                    &Bs[cur][swz(wn * 64 + c * 16 + r16, g0)]);
        }
#pragma unroll
        for (int kk = 0; kk < 2; ++kk) {            // group 3: bg1 (4 reads)
            const int g0 = (kk << 2) + quad;
#pragma unroll
            for (int c = 0; c < 2; ++c)
                bg[1][c][kk] = *reinterpret_cast<const bf16x8*>(
                    &Bs[cur][swz(wn * 64 + (2 + c) * 16 + r16, g0)]);
        }
#pragma unroll
        for (int kk = 0; kk < 2; ++kk) {            // group 4: afB (8 reads)
            const int g0 = (kk << 2) + quad;
#pragma unroll
            for (int r = 0; r < 4; ++r)
                afB[r][kk] = *reinterpret_cast<const bf16x8*>(
                    &As[cur][swz(wm * 128 + (4 + r) * 16 + r16, g0)]);
        }

        // Q00/Q01 under counted lgkm waits; bg1/afB drain underneath.
        __builtin_amdgcn_s_setprio(1);
#pragma unroll
        for (int kk = 0; kk < 2; ++kk)
#pragma unroll
            for (int r = 0; r < 4; ++r)
#pragma unroll
                for (int c = 0; c < 2; ++c)
                    acc[r][c] = __builtin_amdgcn_mfma_f32_16x16x32_bf16(
                        afA[r][kk], bg[0][c][kk], acc[r][c], 0, 0, 0);
#pragma unroll
        for (int kk = 0; kk < 2; ++kk)
#pragma unroll
            for (int r = 0; r < 4; ++r)
#pragma unroll
                for (int c = 0; c < 2; ++c)
                    acc[r][2 + c] = __builtin_amdgcn_mfma_f32_16x16x32_bf16(
                        afA[r][kk], bg[1][c][kk], acc[r][2 + c], 0, 0, 0);
        __builtin_amdgcn_s_setprio(0);

        __builtin_amdgcn_sched_barrier(0);          // pin all read issues above
        WAIT_LGKM0;                                 // all 24 reads complete
        __builtin_amdgcn_s_barrier();               // LDS WAR fence: buf[cur] free
        if (ti + 2 < T) prefetch(ti + 2, cur);      // 8 gld16, covered by Q10/Q11

        __builtin_amdgcn_s_setprio(1);
#pragma unroll
        for (int kk = 0; kk < 2; ++kk)
#pragma unroll
            for (int r = 0; r < 4; ++r)
#pragma unroll
                for (int c = 0; c < 2; ++c)
                    acc[4 + r][c] = __builtin_amdgcn_mfma_f32_16x16x32_bf16(
                        afB[r][kk], bg[0][c][kk], acc[4 + r][c], 0, 0, 0);
#pragma unroll
        for (int kk = 0; kk < 2; ++kk)
#pragma unroll
            for (int r = 0; r < 4; ++r)
#pragma unroll
                for (int c = 0; c < 2; ++c)
                    acc[4 + r][2 + c] = __builtin_amdgcn_mfma_f32_16x16x32_bf16(
                        afB[r][kk], bg[1][c][kk], acc[4 + r][2 + c], 0, 0, 0);
        __builtin_amdgcn_s_setprio(0);
    }

#pragma unroll
    for (int r = 0; r < 8; ++r) {
#pragma unroll
        for (int c = 0; c < 4; ++c) {
            const long gcol = col0 + wn * 64 + c * 16 + r16;
            float bv = 0.f;
            if (bias) bv = (gcol < nsplit) ? bias[gcol] : bias2[gcol - nsplit];
#pragma unroll
            for (int i = 0; i < 4; ++i) {
                const long grow = row0 + wm * 128 + r * 16 + quad * 4 + i;
                float val = acc[r][c][i] + bv;
                if (mode == 0) {
                    ((float*)C)[(long)z * bsC + grow * ldc + gcol] = val;
                } else {
                    bf16* Cb = (bf16*)C + (long)z * bsC;
                    bf16 h = (bf16)val;
                    Cb[grow * ldc + gcol] = h;
                    Cb[psC + grow * ldc + gcol] = (bf16)(val - (float)h);
                }
            }
        }
    }
}

// Sum two split-K PV partials + resid*scale -> bf16 plane-pair.
// Partials: [4][2048][512] f32 each (p1 = p0 + 4*2048*512). resid is the
// contiguous f32 [4][2048][512] input. outp points at the target column
// block of temp ([z][2048][1024] rows); lo plane at outp + psC.
__global__ __launch_bounds__(256) void reduce_pv(
    const float* __restrict__ p0, const float* __restrict__ p1,
    const float* __restrict__ resid, const float* __restrict__ scale,
    bf16* __restrict__ outp, long psC)
{
    const long gid = (long)blockIdx.x * 256 + threadIdx.x;
    const long f4  = gid * 4;                     // over [0, 4*2048*512)
    const long z   = f4 >> 20;                    // 2048*512 = 1<<20
    const long rem = f4 & ((1L << 20) - 1);
    const long row = rem >> 9;
    const long col = rem & 511;
    const float scv = *scale;
    f32x4 a = *reinterpret_cast<const f32x4*>(p0 + f4);
    f32x4 b = *reinterpret_cast<const f32x4*>(p1 + f4);
    f32x4 r = *reinterpret_cast<const f32x4*>(resid + f4);
    bf16x4 h, l;
#pragma unroll
    for (int j = 0; j < 4; ++j) {
        float v = a[j] + b[j] + r[j] * scv;
        h[j] = (bf16)v;
        l[j] = (bf16)(v - (float)h[j]);
    }
    bf16* dst = outp + z * (2048L * 1024) + row * 1024 + col;
    *reinterpret_cast<bf16x4*>(dst) = h;
    *reinterpret_cast<bf16x4*>(dst + psC) = l;
}

// Row softmax over 2048 f32 cols; writes P IN PLACE as bf16 hi plane (cols
// [0,2048) of the row's 4096 bf16 slots) and lo plane (cols [2048,4096)).
__global__ __launch_bounds__(256) void softmax_planes(float* __restrict__ S)
{
    __shared__ float redm[4], reds[4];
    float* srow = S + (long)blockIdx.x * 2048;
    const int t = threadIdx.x;
    const int lane = t & 63;
    const int wave = t >> 6;

    f32x4 v0 = *reinterpret_cast<const f32x4*>(srow + t * 4);
    f32x4 v1 = *reinterpret_cast<const f32x4*>(srow + 1024 + t * 4);

    float m = v0[0];
#pragma unroll
    for (int i = 1; i < 4; ++i) m = fmaxf(m, v0[i]);
#pragma unroll
    for (int i = 0; i < 4; ++i) m = fmaxf(m, v1[i]);
#pragma unroll
    for (int off = 32; off > 0; off >>= 1) m = fmaxf(m, __shfl_xor(m, off));
    if (lane == 0) redm[wave] = m;
    __syncthreads();
    m = fmaxf(fmaxf(redm[0], redm[1]), fmaxf(redm[2], redm[3]));

    float s = 0.f;
#pragma unroll
    for (int i = 0; i < 4; ++i) { v0[i] = __expf(v0[i] - m); s += v0[i]; }
#pragma unroll
    for (int i = 0; i < 4; ++i) { v1[i] = __expf(v1[i] - m); s += v1[i]; }
#pragma unroll
    for (int off = 32; off > 0; off >>= 1) s += __shfl_xor(s, off);
    if (lane == 0) reds[wave] = s;
    __syncthreads();
    s = reds[0] + reds[1] + reds[2] + reds[3];
    float inv = 1.f / s;

    bf16x4 h0, h1, l0, l1;
#pragma unroll
    for (int i = 0; i < 4; ++i) {
        float a = v0[i] * inv, b = v1[i] * inv;
        h0[i] = (bf16)a; l0[i] = (bf16)(a - (float)h0[i]);
        h1[i] = (bf16)b; l1[i] = (bf16)(b - (float)h1[i]);
    }
    bf16* ph = (bf16*)srow;
    *reinterpret_cast<bf16x4*>(ph + t * 4) = h0;
    *reinterpret_cast<bf16x4*>(ph + 1024 + t * 4) = h1;
    *reinterpret_cast<bf16x4*>(ph + 2048 + t * 4) = l0;
    *reinterpret_cast<bf16x4*>(ph + 3072 + t * 4) = l1;
}

// f32[n] -> hi bf16 at hi[i], lo bf16 at lo[i]. n % 1024 == 0.
__global__ __launch_bounds__(256) void split2_f32(
    const float* __restrict__ in, bf16* __restrict__ hi, bf16* __restrict__ lo)
{
    long i = ((long)blockIdx.x * 256 + threadIdx.x) * 4;
    f32x4 v = *reinterpret_cast<const f32x4*>(in + i);
    bf16x4 h, l;
#pragma unroll
    for (int j = 0; j < 4; ++j) {
        h[j] = (bf16)v[j];
        l[j] = (bf16)(v[j] - (float)h[j]);
    }
    *reinterpret_cast<bf16x4*>(hi + i) = h;
    *reinterpret_cast<bf16x4*>(lo + i) = l;
}

extern "C" void kernel_launch(void* const* d_in, const int* in_sizes, int n_in,
                              void* d_out, int out_size, void* d_ws, size_t ws_size,
                              hipStream_t stream)
{
    const float* x   = (const float*)d_in[0];
    const float* y   = (const float*)d_in[1];
    const float* Wq1 = (const float*)d_in[2];
    const float* bq1 = (const float*)d_in[3];
    const float* Wk1 = (const float*)d_in[4];
    const float* bk1 = (const float*)d_in[5];
    const float* Wv1 = (const float*)d_in[6];
    const float* bv1 = (const float*)d_in[7];
    const float* Wq2 = (const float*)d_in[8];
    const float* bq2 = (const float*)d_in[9];
    const float* Wk2 = (const float*)d_in[10];
    const float* bk2 = (const float*)d_in[11];
    const float* Wv2 = (const float*)d_in[12];
    const float* bv2 = (const float*)d_in[13];
    const float* w1  = (const float*)d_in[14];
    const float* w2  = (const float*)d_in[15];
    float* out = (float*)d_out;

    const size_t MB = 1ull << 20;
    char* ws = (char*)d_ws;
    const long S = 2048, M4 = 8192, E1 = 512, E2 = 1024;
    const long W1ps = E1 * E1, W2ps = E2 * E2;

    const int cfg = (ws_size >= 207 * MB) ? 2 : 0;

    auto gemm = [&](const bf16* A, long lda, long psA, long bsA,
                    const bf16* B, long ldb, long psB, long bsB,
                    void* C, long ldc, long psC, long bsC, int mode,
                    const float* bias, const float* bias2, int nsplit,
                    const float* resid, long ldr, long bsR,
                    const float* scale, int M, int N, int K, int split,
                    int gz, int nz) {
        int nx = N / 128, ny = M / 128;
        dim3 g((unsigned)(nx * ny * gz));
        gemm_split<<<g, dim3(256), 0, stream>>>(
            A, lda, psA, bsA, B, ldb, psB, bsB, C, ldc, psC, bsC, mode,
            bias, bias2, nsplit, resid, ldr, bsR, scale, K, split, nx, ny, nz);
    };
    auto g256 = [&](const bf16* A, long lda, long psA, long bsA,
                    const bf16* B, long ldb, long psB, long bsB,
                    void* C, long ldc, long psC, long bsC, int mode,
                    const float* bias, const float* bias2, int nsplit,
                    int K, int split, int M, int N, int gz) {
        int nx = N / 256, ny = M / 256;
        gemm256<<<dim3((unsigned)(nx * ny * gz)), dim3(512), 0, stream>>>(
            A, lda, psA, bsA, B, ldb, psB, bsB, C, ldc, psC, bsC, mode,
            bias, bias2, nsplit, K, split, nx, ny);
    };
    auto conv2 = [&](const float* in, bf16* hi, bf16* lo, long n) {
        split2_f32<<<dim3((unsigned)(n / 1024)), dim3(256), 0, stream>>>(in, hi, lo);
    };

    if (cfg == 2) {
        // --- buffers ---
        bf16* xyp   = (bf16*)d_out;            // [2][16384][512] planes; dead after projections
        bf16* Wqk1p = (bf16*)(ws + 0 * MB);    // [2][1024][512] stacked Q|K (2MB)
        bf16* Wv1p  = (bf16*)(ws + 2 * MB);    // [2][512][512] (1MB)
        bf16* Wqk2p = (bf16*)(ws + 3 * MB);    // [2][2048][1024] stacked Q|K (8MB)
        bf16* Wv2p  = (bf16*)(ws + 11 * MB);   // [2][1024][1024] (4MB)
        bf16* temp  = (bf16*)(ws + 15 * MB);   // [2][8192][1024] (32MB)
        bf16* qk    = (bf16*)(ws + 47 * MB);   // stage1: [2][16384][1024]; stage2: [2][8192][2048] (64MB)
        bf16* vt    = (bf16*)(ws + 111 * MB);  // stage1: [8][2][512][2048]; stage2: [4][2][1024][2048] (32MB)
        float* Sc   = (float*)(ws + 143 * MB); // [4][2048][2048] f32 (64MB)

        const long PXY = 16384L * 512;         // xyp plane
        const long PW1 = 1024L * 512;          // Wqk1 plane
        const long PW2 = 2048L * 1024;         // Wqk2 plane
        const long PQ1 = 16384L * 1024;        // stage1 qk plane
        const long PQ2 = 8192L * 2048;         // stage2 qk plane (same bytes)
        const long PT  = 8192L * 1024;         // temp plane
        const long BV1 = 2 * E1 * S;           // vt batch stride stage1
        const long BV2 = 2 * E2 * S;           // stage2
        const long PVH = 4L * 2048 * 512;      // PV split-K half stride (f32)
        float* pvScr = (float*)d_out;          // 32MB scratch (xyp dead by PV time)

        // --- split inputs & weights ---
        conv2(x, xyp, xyp + PXY, M4 * E1);
        conv2(y, xyp + M4 * E1, xyp + PXY + M4 * E1, M4 * E1);
        conv2(Wq1, Wqk1p, Wqk1p + PW1, W1ps);
        conv2(Wk1, Wqk1p + W1ps, Wqk1p + PW1 + W1ps, W1ps);
        conv2(Wv1, Wv1p, Wv1p + W1ps, W1ps);
        conv2(Wq2, Wqk2p, Wqk2p + PW2, W2ps);
        conv2(Wk2, Wqk2p + W2ps, Wqk2p + PW2 + W2ps, W2ps);
        conv2(Wv2, Wv2p, Wv2p + W2ps, W2ps);

        // --- stage 1: batched projections (x|y rows, Q|K cols) ---
        g256(xyp, E1, PXY, 0, Wqk1p, E1, PW1, 0,
             qk, 1024, PQ1, 0, 1, bq1, bk1, 512,
             512, 3, 16384, 1024, 1);
        gemm(xyp, E1, PXY, 0, Wv1p, E1, W1ps, 0,
             vt, S, E1 * S, BV1, 2, bv1, nullptr, 512,
             nullptr, 0, 0, nullptr, 16384, 512, 512, 3, 1, 1);

        // --- x path: scores -> softmax -> PV split-K (+ y*w2) -> temp cols 0-511 ---
        g256(qk, 1024, PQ1, S * 1024, qk + 512, 1024, PQ1, S * 1024,
             Sc, S, 0, S * S, 0, nullptr, nullptr, 0, 512, 3, 2048, 2048, 4);
        softmax_planes<<<dim3(8192), dim3(256), 0, stream>>>(Sc);
        gemm((const bf16*)Sc, 4096, 2048, S * 4096, vt, S, E1 * S, BV1,
             pvScr, 512, PVH, 2048L * 512, 3, nullptr, nullptr, 0,
             nullptr, 0, 0, nullptr, 2048, 512, 1024, 3, 8, 4);
        reduce_pv<<<dim3(4096), dim3(256), 0, stream>>>(
            pvScr, pvScr + PVH, y, w2, temp, PT);

        // --- y path ---
        g256(qk + M4 * 1024, 1024, PQ1, S * 1024,
             qk + M4 * 1024 + 512, 1024, PQ1, S * 1024,
             Sc, S, 0, S * S, 0, nullptr, nullptr, 0, 512, 3, 2048, 2048, 4);
        softmax_planes<<<dim3(8192), dim3(256), 0, stream>>>(Sc);
        gemm((const bf16*)Sc, 4096, 2048, S * 4096, vt + 4 * BV1, S, E1 * S, BV1,
             pvScr, 512, PVH, 2048L * 512, 3, nullptr, nullptr, 0,
             nullptr, 0, 0, nullptr, 2048, 512, 1024, 3, 8, 4);
        reduce_pv<<<dim3(4096), dim3(256), 0, stream>>>(
            pvScr, pvScr + PVH, x, w1, temp + 512, PT);

        // --- stage 2 ---
        g256(temp, E2, PT, 0, Wqk2p, E2, PW2, 0,
             qk, 2048, PQ2, 0, 1, bq2, bk2, 1024,
             1024, 3, 8192, 2048, 1);
        gemm(temp, E2, PT, 0, Wv2p, E2, W2ps, 0,
             vt, S, E2 * S, BV2, 2, bv2, nullptr, 1024,
             nullptr, 0, 0, nullptr, 8192, 1024, 1024, 1, 1, 1);
        g256(qk, 2048, PQ2, S * 2048, qk + 1024, 2048, PQ2, S * 2048,
             Sc, S, 0, S * S, 0, nullptr, nullptr, 0, 1024, 3, 2048, 2048, 4);
        softmax_planes<<<dim3(8192), dim3(256), 0, stream>>>(Sc);
        gemm((const bf16*)Sc, 4096, 2048, S * 4096, vt, S, E2 * S, BV2,
             out, E2, 0, S * E2, 0, nullptr, nullptr, 1024,
             nullptr, 0, 0, nullptr, 2048, 1024, 2048, 1, 4, 4);
    } else {
        // --- legacy small-workspace path (original layout, per-batch loops) ---
        bf16* xp = (bf16*)d_out;
        bf16* yp = xp + 2 * M4 * E1;
        bf16* Wq1p = (bf16*)(ws + 0 * MB);
        bf16* Wk1p = (bf16*)(ws + 1 * MB);
        bf16* Wv1p = (bf16*)(ws + 2 * MB);
        bf16* temp = (bf16*)(ws + 3 * MB);
        bf16* qb   = (bf16*)(ws + 35 * MB);
        bf16* kb   = (bf16*)(ws + 43 * MB);
        bf16* vt   = (bf16*)(ws + 51 * MB);
        float* Sc  = (float*)(ws + 59 * MB);
        bf16* Wq2p = (bf16*)d_out;
        bf16* Wk2p = Wq2p + 2 * W2ps;
        bf16* Wv2p = Wk2p + 2 * W2ps;

        conv2(x, xp, xp + M4 * E1, M4 * E1);
        conv2(y, yp, yp + M4 * E1, M4 * E1);
        conv2(Wq1, Wq1p, Wq1p + W1ps, W1ps);
        conv2(Wk1, Wk1p, Wk1p + W1ps, W1ps);
        conv2(Wv1, Wv1p, Wv1p + W1ps, W1ps);

        auto stage1 = [&](const bf16* sp, const float* resid, const float* scale, long colOff) {
            for (int b = 0; b < 4; ++b) {
                const bf16* sb = sp + (long)b * S * E1;
                gemm(sb, E1, M4 * E1, 0, Wq1p, E1, W1ps, 0, qb, E1, S * E1, 0, 1,
                     bq1, nullptr, 512, nullptr, 0, 0, nullptr, 2048, 512, 512, 3, 1, 1);
                gemm(sb, E1, M4 * E1, 0, Wk1p, E1, W1ps, 0, kb, E1, S * E1, 0, 1,
                     bk1, nullptr, 512, nullptr, 0, 0, nullptr, 2048, 512, 512, 3, 1, 1);
                gemm(sb, E1, M4 * E1, 0, Wv1p, E1, W1ps, 0, vt, S, E1 * S, 0, 2,
                     bv1, nullptr, 512, nullptr, 0, 0, nullptr, 2048, 512, 512, 3, 1, 1);
                gemm(qb, E1, S * E1, 0, kb, E1, S * E1, 0, Sc, S, 0, 0, 0,
                     nullptr, nullptr, 2048, nullptr, 0, 0, nullptr, 2048, 2048, 512, 3, 1, 1);
                softmax_planes<<<dim3(2048), dim3(256), 0, stream>>>(Sc);
                gemm((const bf16*)Sc, 4096, 2048, 0, vt, S, E1 * S, 0,
                     temp + colOff + (long)b * S * 1024, 1024, M4 * 1024, 0, 1,
                     nullptr, nullptr, 512, resid + (long)b * S * E1, E1, 0, scale,
                     2048, 512, 2048, 3, 1, 1);
            }
        };

        stage1(xp, y, w2, 0);
        stage1(yp, x, w1, 512);

        conv2(Wq2, Wq2p, Wq2p + W2ps, W2ps);
        conv2(Wk2, Wk2p, Wk2p + W2ps, W2ps);
        conv2(Wv2, Wv2p, Wv2p + W2ps, W2ps);

        for (int b = 0; b < 4; ++b) {
            const bf16* tb = temp + (long)b * S * E2;
            gemm(tb, E2, M4 * E2, 0, Wq2p, E2, W2ps, 0, qb, E2, S * E2, 0, 1,
                 bq2, nullptr, 1024, nullptr, 0, 0, nullptr, 2048, 1024, 1024, 3, 1, 1);
            gemm(tb, E2, M4 * E2, 0, Wk2p, E2, W2ps, 0, kb, E2, S * E2, 0, 1,
                 bk2, nullptr, 1024, nullptr, 0, 0, nullptr, 2048, 1024, 1024, 3, 1, 1);
            gemm(tb, E2, M4 * E2, 0, Wv2p, E2, W2ps, 0, vt, S, E2 * S, 0, 2,
                 bv2, nullptr, 1024, nullptr, 0, 0, nullptr, 2048, 1024, 1024, 1, 1, 1);
            gemm(qb, E2, S * E2, 0, kb, E2, S * E2, 0, Sc, S, 0, 0, 0,
                 nullptr, nullptr, 2048, nullptr, 0, 0, nullptr, 2048, 2048, 1024, 3, 1, 1);
            softmax_planes<<<dim3(2048), dim3(256), 0, stream>>>(Sc);
            gemm((const bf16*)Sc, 4096, 2048, 0, vt, S, E2 * S, 0,
                 out + (long)b * S * E2, E2, 0, 0, 0, nullptr, nullptr, 1024,
                 nullptr, 0, 0, nullptr, 2048, 1024, 2048, 1, 1, 1);
        }
    }

    (void)in_sizes; (void)n_in; (void)out_size;
}